// Round 1
// 1458.549 us; speedup vs baseline: 1.0652x; 1.0652x over previous
//
#include <hip/hip_runtime.h>
#include <hip/hip_bf16.h>
#include <math.h>

#define BB 2
#define NN 2048
#define MM 2048
#define DIMD 1024
#define HH 8
#define DHD 64
#define INNERD 512
#define FFD 8192
#define SCALE_QK 0.125f

typedef __hip_bfloat16 bf16;
typedef float f32x4 __attribute__((ext_vector_type(4)));
typedef short short8 __attribute__((ext_vector_type(8)));
static const long long NM = (long long)NN * MM;

__device__ __forceinline__ float cvt(float v) { return v; }
__device__ __forceinline__ float cvt(bf16 v) { return __bfloat162float(v); }
__device__ __forceinline__ void stc(float* p, float v) { *p = v; }
__device__ __forceinline__ void stc(bf16* p, float v) { *p = __float2bfloat16(v); }

__device__ __forceinline__ void gl_lds16(const bf16* g, bf16* l) {
    __builtin_amdgcn_global_load_lds(
        (const __attribute__((address_space(1))) void*)(g),
        (__attribute__((address_space(3))) void*)(l), 16, 0, 0);
}

// ---------------- reductions ----------------
__device__ __forceinline__ float block_reduce_sum(float v) {
    __shared__ float sh[4];
    int tid = threadIdx.x;
#pragma unroll
    for (int off = 32; off > 0; off >>= 1) v += __shfl_down(v, off, 64);
    __syncthreads();
    if ((tid & 63) == 0) sh[tid >> 6] = v;
    __syncthreads();
    return sh[0] + sh[1] + sh[2] + sh[3];
}

__device__ __forceinline__ float block_reduce_max(float v) {
    __shared__ float sh[4];
    int tid = threadIdx.x;
#pragma unroll
    for (int off = 32; off > 0; off >>= 1) v = fmaxf(v, __shfl_down(v, off, 64));
    __syncthreads();
    if ((tid & 63) == 0) sh[tid >> 6] = v;
    __syncthreads();
    return fmaxf(fmaxf(sh[0], sh[1]), fmaxf(sh[2], sh[3]));
}

// ---------------- layernorm: fp32 in -> bf16 out ----------------
__global__ __launch_bounds__(256) void layernorm_k(const float* __restrict__ in,
                                                   bf16* __restrict__ out,
                                                   const float* __restrict__ g,
                                                   const float* __restrict__ b) {
    long long row = blockIdx.x;
    const float* xr = in + row * DIMD;
    bf16* yr = out + row * DIMD;
    int tid = threadIdx.x;
    float s = 0.f;
    for (int i = tid; i < DIMD; i += 256) s += xr[i];
    float mean = block_reduce_sum(s) * (1.0f / DIMD);
    float s2 = 0.f;
    for (int i = tid; i < DIMD; i += 256) { float d = xr[i] - mean; s2 += d * d; }
    float var = block_reduce_sum(s2) * (1.0f / DIMD);
    float inv = 1.0f / sqrtf(var + 1e-5f);
    for (int i = tid; i < DIMD; i += 256)
        yr[i] = __float2bfloat16((xr[i] - mean) * inv * g[i] + b[i]);
}

// ---------------- bias add (fp32, vectorized) ----------------
__global__ __launch_bounds__(256) void biasadd_k(float* __restrict__ out,
                                                 const float* __restrict__ bias) {
    long long idx = (long long)blockIdx.x * 256 + threadIdx.x;  // float4 index
    f32x4 v = ((f32x4*)out)[idx];
    const f32x4 bv = ((const f32x4*)bias)[idx & (DIMD / 4 - 1)];
    v.x += bv.x; v.y += bv.y; v.z += bv.z; v.w += bv.w;
    ((f32x4*)out)[idx] = v;
}

// ---------------- transpose + convert: in [R][C] -> out bf16 [C][R] ----------------
template <typename TI>
__global__ __launch_bounds__(256) void transpose_k(const TI* __restrict__ in,
                                                   bf16* __restrict__ out,
                                                   int R, int C) {
    __shared__ bf16 t[32][33];
    int bc = blockIdx.x * 32, br = blockIdx.y * 32;
    int tid = threadIdx.x;
    int c = tid & 31, r0 = tid >> 5;
#pragma unroll
    for (int s = 0; s < 4; s++) {
        int r = r0 + s * 8;
        t[r][c] = __float2bfloat16(cvt(in[(long long)(br + r) * C + bc + c]));
    }
    __syncthreads();
#pragma unroll
    for (int s = 0; s < 4; s++) {
        int r = r0 + s * 8;
        out[(long long)(bc + r) * R + br + c] = t[c][r];
    }
}

// ---------------- col softmax stats over i: partial then combine ----------------
__global__ __launch_bounds__(256) void colstats_part_k(const bf16* __restrict__ sim,
                                                       float* __restrict__ mcp,
                                                       float* __restrict__ lcp) {
    int j = blockIdx.x * 256 + threadIdx.x;
    int h = blockIdx.y;
    int ic = blockIdx.z;
    const bf16* base = sim + (long long)h * NM;
    float m = -3.4e38f, s = 0.f;
    for (int i = ic * 256; i < ic * 256 + 256; i++) {
        float v = cvt(base[(long long)i * MM + j]);
        float nm = fmaxf(m, v);
        s = s * expf(m - nm) + expf(v - nm);
        m = nm;
    }
    mcp[((long long)ic * HH + h) * MM + j] = m;
    lcp[((long long)ic * HH + h) * MM + j] = s;
}

__global__ __launch_bounds__(256) void colstats_comb_k(const float* __restrict__ mcp,
                                                       const float* __restrict__ lcp,
                                                       float* __restrict__ mc,
                                                       float* __restrict__ lc) {
    int idx = blockIdx.x * 256 + threadIdx.x;  // h*MM + j
    int h = idx >> 11, j = idx & (MM - 1);
    float m = -3.4e38f;
#pragma unroll
    for (int ic = 0; ic < 8; ic++) m = fmaxf(m, mcp[((long long)ic * HH + h) * MM + j]);
    float l = 0.f;
#pragma unroll
    for (int ic = 0; ic < 8; ic++)
        l += lcp[((long long)ic * HH + h) * MM + j] * expf(mcp[((long long)ic * HH + h) * MM + j] - m);
    mc[idx] = m;
    lc[idx] = l;
}

// ---------------- col path: normalize + mix + transpose, sim -> simT ----------------
__global__ __launch_bounds__(256) void mixcolT_k(const bf16* __restrict__ sim,
                                                 bf16* __restrict__ simT,
                                                 const float* __restrict__ w,
                                                 const float* __restrict__ mc,
                                                 const float* __restrict__ lc) {
    __shared__ bf16 t[HH][32][33];
    __shared__ float ws_[64];
    int j0 = blockIdx.x * 32, i0 = blockIdx.y * 32;
    int tid = threadIdx.x;
    if (tid < 64) ws_[tid] = w[tid];
    int jj = tid & 31, r0 = tid >> 5;
#pragma unroll
    for (int h = 0; h < HH; h++)
#pragma unroll
        for (int s = 0; s < 4; s++) {
            int ii = r0 + s * 8;
            t[h][ii][jj] = sim[h * NM + (long long)(i0 + ii) * MM + j0 + jj];
        }
    __syncthreads();
    int il = tid & 31, c0 = tid >> 5;
#pragma unroll
    for (int s = 0; s < 4; s++) {
        int jl = c0 + s * 8;
        int jg = j0 + jl;
        float p[HH];
#pragma unroll
        for (int h = 0; h < HH; h++)
            p[h] = expf(cvt(t[h][il][jl]) - mc[h * MM + jg]) * (1.0f / lc[h * MM + jg]);
#pragma unroll
        for (int g = 0; g < HH; g++) {
            float o = 0.f;
#pragma unroll
            for (int h = 0; h < HH; h++) o += ws_[g * 8 + h] * p[h];
            simT[g * NM + (long long)jg * MM + i0 + il] = __float2bfloat16(o);
        }
    }
}

// ---------------- row path: fused row-stats + normalize + mix, in place ----------------
__global__ __launch_bounds__(256) void rowsoftmix_k(bf16* __restrict__ sim,
                                                    const float* __restrict__ w) {
    __shared__ float ws_[64];
    int i = blockIdx.x, tid = threadIdx.x;
    if (tid < 64) ws_[tid] = w[tid];
    float v[HH][8];
#pragma unroll
    for (int h = 0; h < HH; h++)
#pragma unroll
        for (int c = 0; c < 8; c++)
            v[h][c] = cvt(sim[h * NM + (long long)i * MM + tid + c * 256]);
    float mh[HH], lh[HH];
#pragma unroll
    for (int h = 0; h < HH; h++) {
        float m = v[h][0];
#pragma unroll
        for (int c = 1; c < 8; c++) m = fmaxf(m, v[h][c]);
        mh[h] = block_reduce_max(m);
    }
#pragma unroll
    for (int h = 0; h < HH; h++) {
        float s = 0.f;
#pragma unroll
        for (int c = 0; c < 8; c++) s += expf(v[h][c] - mh[h]);
        lh[h] = 1.0f / block_reduce_sum(s);
    }
    __syncthreads();
#pragma unroll
    for (int c = 0; c < 8; c++) {
        float p[HH];
#pragma unroll
        for (int h = 0; h < HH; h++) p[h] = expf(v[h][c] - mh[h]) * lh[h];
#pragma unroll
        for (int g = 0; g < HH; g++) {
            float o = 0.f;
#pragma unroll
            for (int h = 0; h < HH; h++) o += ws_[g * 8 + h] * p[h];
            sim[g * NM + (long long)i * MM + tid + c * 256] = __float2bfloat16(o);
        }
    }
}

// ---------------- MFMA bf16 GEMM (128^2, 2-barrier; kept for small/odd shapes) ----------------
// C[m,n] = alpha * sum_k A[m][k] * B[n][k]  (+bias[n]) (+residual[m,n]) (->gelu)
template <int BM, int BN, int WROWS, int ZMODE, bool ATOMIC, typename CT>
__global__ __launch_bounds__(256) void mgemm(
    const bf16* __restrict__ A, const bf16* __restrict__ B, CT* __restrict__ C,
    int K, int lda, int ldb, int ldc,
    long long sA, long long sB, long long sC,
    float alpha, const float* __restrict__ bias, const float* __restrict__ bias2,
    const float* __restrict__ residual, const float* __restrict__ residual2,
    int ldr, int gelu_flag) {
    constexpr int BK = 32;
    constexpr int WCOLS = 4 / WROWS;
    constexpr int WM = BM / WROWS, WN = BN / WCOLS;
    constexpr int FM = WM / 16, FN = WN / 16;
    constexpr int ACH = BM * BK / 8;
    constexpr int BCH = BN * BK / 8;
    __shared__ bf16 As[BM * BK];
    __shared__ bf16 Bs[BN * BK];
    int z = blockIdx.z;
    int m0 = blockIdx.y * BM, n0 = blockIdx.x * BN;
    if (ZMODE == 0) A += z * sA;
    else if (ZMODE == 1) A += (long long)(z >> 1) * sA;
    else if (ZMODE == 2) A += ((long long)(((m0 >> 11) << 1) + z) * 2048 - m0) * lda;
    B += z * sB;
    C += z * sC;
    const float* bb_ = bias;
    const float* rr_ = residual;
    if (ZMODE == 2 && z) { bb_ = bias2; rr_ = residual2; }
    int tid = threadIdx.x, lane = tid & 63, w = tid >> 6;
    int wm = (w / WCOLS) * WM, wn = (w % WCOLS) * WN;
    f32x4 acc[FM][FN] = {};
    for (int k0 = 0; k0 < K; k0 += BK) {
        __syncthreads();
#pragma unroll
        for (int c = tid; c < ACH; c += 256) {
            int row = c >> 2, col = (c & 3) * 8;
            gl_lds16(A + (long long)(m0 + row) * lda + k0 + col, As + c * 8);
        }
#pragma unroll
        for (int c = tid; c < BCH; c += 256) {
            int row = c >> 2, col = (c & 3) * 8;
            gl_lds16(B + (long long)(n0 + row) * ldb + k0 + col, Bs + c * 8);
        }
        __syncthreads();
        short8 af[FM], bfr[FN];
#pragma unroll
        for (int fm = 0; fm < FM; fm++)
            af[fm] = *(const short8*)&As[(wm + fm * 16 + (lane & 15)) * BK + (lane >> 4) * 8];
#pragma unroll
        for (int fn = 0; fn < FN; fn++)
            bfr[fn] = *(const short8*)&Bs[(wn + fn * 16 + (lane & 15)) * BK + (lane >> 4) * 8];
#pragma unroll
        for (int fm = 0; fm < FM; fm++)
#pragma unroll
            for (int fn = 0; fn < FN; fn++)
                acc[fm][fn] = __builtin_amdgcn_mfma_f32_16x16x32_bf16(af[fm], bfr[fn], acc[fm][fn], 0, 0, 0);
    }
#pragma unroll
    for (int fm = 0; fm < FM; fm++) {
#pragma unroll
        for (int fn = 0; fn < FN; fn++) {
#pragma unroll
            for (int r = 0; r < 4; r++) {
                int m = m0 + wm + fm * 16 + (lane >> 4) * 4 + r;
                int n = n0 + wn + fn * 16 + (lane & 15);
                float v = acc[fm][fn][r] * alpha;
                if (bb_) v += bb_[n];
                if (rr_) v += rr_[(long long)m * ldr + n];
                if (gelu_flag) v = 0.5f * v * (1.0f + erff(v * 0.70710678118654752440f));
                if (ATOMIC) atomicAdd((float*)&C[(long long)m * ldc + n], v);
                else stc(&C[(long long)m * ldc + n], v);
            }
        }
    }
}

// ---------------- 256x256 8-phase MFMA GEMM (T2+T3+T4+T5) ----------------
// C[m,n] = sum_k A[m][k]*B[n][k] (+bias[n]) (->gelu) ; per-z offsets like ZMODE 0.
// 8 waves (2Mx4N), per-wave 128x64 out, BK=64, double-buffered 128 KiB LDS,
// XOR-swizzle cb^=(row&7)<<4 on ds_read_b128 (stage side pre-swizzles global src),
// counted s_waitcnt vmcnt(4) once per K-tile, raw s_barrier (no vmcnt(0) drain),
// s_setprio(1) around the 16-MFMA cluster.
template <bool GELU, bool ATOMIC, typename CT>
__global__ __launch_bounds__(512, 2) void mgemm256(
    const bf16* __restrict__ A, const bf16* __restrict__ B, CT* __restrict__ C,
    int K, int lda, int ldb, int ldc,
    long long sA, long long sB, long long sC,
    const float* __restrict__ bias) {
    // LDS: As[2][256*64] | Bs[2][256*64]  (bf16) = 131072 B
    __shared__ bf16 sm[65536];
    const int T = K >> 6;  // K-tiles of 64
    int z = blockIdx.z;
    A += (long long)z * sA;
    B += (long long)z * sB;
    C += (long long)z * sC;
    // bijective XCD swizzle over the (x,y) plane (nwg % 8 == 0 in all callers)
    int gx = gridDim.x;
    int nwg = gx * gridDim.y;
    int id = blockIdx.y * gx + blockIdx.x;
    id = (id & 7) * (nwg >> 3) + (id >> 3);
    int n0 = (id % gx) * 256;
    int m0 = (id / gx) * 256;

    int tid = threadIdx.x, lane = tid & 63, w = tid >> 6;
    int wrow = w >> 2, wcol = w & 3;
    // staging decomposition: thread handles rows sr, sr+64 of a 128x64 half-tile,
    // 16B chunk at linear LDS byte tid*16 (+8192 for chunk 1).
    int sr = tid >> 3;                       // 0..63
    int ecol = (((tid >> 3) ^ tid) & 7) * 8; // pre-swizzled global col (elements)

    auto stage = [&](const bf16* g, int ld, int row0, int k0, bf16* l) {
        const bf16* s = g + (long long)(row0 + sr) * ld + k0 + ecol;
        gl_lds16(s, l + (tid << 3));
        gl_lds16(s + (long long)(ld << 6), l + 4096 + (tid << 3));
    };

    f32x4 acc[8][4] = {};

    // ---- prologue: A0(h0,h1), B0(h0,h1) -> buf0 ; B1(h0,h1) -> buf1 ----
    stage(A, lda, m0, 0, sm);
    stage(A, lda, m0 + 128, 0, sm + 8192);
    stage(B, ldb, n0, 0, sm + 32768);
    stage(B, ldb, n0 + 128, 0, sm + 32768 + 8192);
    if (T > 1) {
        stage(B, ldb, n0, 64, sm + 32768 + 16384);
        stage(B, ldb, n0 + 128, 64, sm + 32768 + 16384 + 8192);
        asm volatile("s_waitcnt vmcnt(4)" ::: "memory");
    } else {
        asm volatile("s_waitcnt vmcnt(0)" ::: "memory");
    }
    __builtin_amdgcn_s_barrier();

    for (int kt = 0; kt < T; ++kt) {
        const int cur = kt & 1, nxt = cur ^ 1;
        const bf16* Ab = sm + cur * 16384;
        const bf16* Bb = sm + 32768 + cur * 16384;
        // B-frags for this K-tile (cached across the 4 phases): 8 ds_read_b128
        short8 bfr[4][4 / 2][0 + 2];  // dummy shape avoided; see below
        (void)bfr;
        short8 bf_[4][2];
#pragma unroll
        for (int fn = 0; fn < 4; fn++)
#pragma unroll
            for (int kk = 0; kk < 2; kk++) {
                int row = wcol * 64 + fn * 16 + (lane & 15);
                int cb = (kk * 64 + ((lane >> 4) << 4)) ^ ((row & 7) << 4);
                bf_[fn][kk] = *(const short8*)((const char*)Bb + row * 128 + cb);
            }
#pragma unroll
        for (int q = 0; q < 4; q++) {
            short8 af[2][2];
#pragma unroll
            for (int i = 0; i < 2; i++)
#pragma unroll
                for (int kk = 0; kk < 2; kk++) {
                    int row = wrow * 128 + (q * 2 + i) * 16 + (lane & 15);
                    int cb = (kk * 64 + ((lane >> 4) << 4)) ^ ((row & 7) << 4);
                    af[i][kk] = *(const short8*)((const char*)Ab + row * 128 + cb);
                }
            if (q == 0) {
                if (kt + 1 < T) stage(A, lda, m0, (kt + 1) << 6, sm + nxt * 16384);
            } else if (q == 1) {
                if (kt + 1 < T) stage(A, lda, m0 + 128, (kt + 1) << 6, sm + nxt * 16384 + 8192);
            } else if (q == 2) {
                if (kt + 2 < T) stage(B, ldb, n0, (kt + 2) << 6, sm + 32768 + cur * 16384);
            } else {
                if (kt + 2 < T) {
                    stage(B, ldb, n0 + 128, (kt + 2) << 6, sm + 32768 + cur * 16384 + 8192);
                    asm volatile("s_waitcnt vmcnt(4)" ::: "memory");
                } else {
                    asm volatile("s_waitcnt vmcnt(0)" ::: "memory");
                }
            }
            __builtin_amdgcn_s_barrier();
            __builtin_amdgcn_s_setprio(1);
#pragma unroll
            for (int i = 0; i < 2; i++)
#pragma unroll
                for (int fn = 0; fn < 4; fn++)
#pragma unroll
                    for (int kk = 0; kk < 2; kk++)
                        acc[q * 2 + i][fn] = __builtin_amdgcn_mfma_f32_16x16x32_bf16(
                            af[i][kk], bf_[fn][kk], acc[q * 2 + i][fn], 0, 0, 0);
            __builtin_amdgcn_s_setprio(0);
            __builtin_amdgcn_s_barrier();
        }
    }

    // ---- epilogue ----
    long long crow0 = m0 + wrow * 128 + ((lane >> 4) << 2);
    int ccol0 = n0 + wcol * 64 + (lane & 15);
#pragma unroll
    for (int fm = 0; fm < 8; fm++)
#pragma unroll
        for (int fn = 0; fn < 4; fn++)
#pragma unroll
            for (int r = 0; r < 4; r++) {
                long long m = crow0 + fm * 16 + r;
                int n = ccol0 + fn * 16;
                float v = acc[fm][fn][r];
                if (bias) v += bias[n];
                if (GELU) v = 0.5f * v * (1.0f + erff(v * 0.70710678118654752440f));
                if (ATOMIC) atomicAdd((float*)&C[m * ldc + n], v);
                else stc(&C[m * ldc + n], v);
            }
}

// ---------------- attention P@V, both paths in one launch ----------------
__global__ __launch_bounds__(256) void pv_k(const bf16* __restrict__ P,
                                            const bf16* __restrict__ Vt,
                                            bf16* __restrict__ O) {
    constexpr int BK = 32;
    __shared__ bf16 As[64 * BK];
    __shared__ bf16 Bs[64 * BK];
    int z = blockIdx.z;
    int h = z & 7, sel = z >> 3;
    const bf16* A = P + (long long)z * NM;
    const bf16* B = Vt + (long long)z * DHD * NN;
    bf16* C = O + (long long)sel * NN * INNERD + h * DHD;
    int m0 = blockIdx.y * 64;
    int tid = threadIdx.x, lane = tid & 63, w = tid >> 6;
    int wm = w * 16;
    f32x4 acc[4] = {};
    for (int k0 = 0; k0 < NN; k0 += BK) {
        __syncthreads();
        {
            int row = tid >> 2, col = (tid & 3) * 8;
            gl_lds16(A + (long long)(m0 + row) * MM + k0 + col, As + tid * 8);
            gl_lds16(B + (long long)row * NN + k0 + col, Bs + tid * 8);
        }
        __syncthreads();
        short8 af = *(const short8*)&As[(wm + (lane & 15)) * BK + (lane >> 4) * 8];
#pragma unroll
        for (int fn = 0; fn < 4; fn++) {
            short8 bfr = *(const short8*)&Bs[(fn * 16 + (lane & 15)) * BK + (lane >> 4) * 8];
            acc[fn] = __builtin_amdgcn_mfma_f32_16x16x32_bf16(af, bfr, acc[fn], 0, 0, 0);
        }
    }
#pragma unroll
    for (int fn = 0; fn < 4; fn++)
#pragma unroll
        for (int r = 0; r < 4; r++) {
            int m = m0 + wm + (lane >> 4) * 4 + r;
            int n = fn * 16 + (lane & 15);
            stc(&C[(long long)m * INNERD + n], acc[fn][r]);
        }
}

extern "C" void kernel_launch(void* const* d_in, const int* in_sizes, int n_in,
                              void* d_out, int out_size, void* d_ws, size_t ws_size,
                              hipStream_t stream) {
    const float* x = (const float*)d_in[0];
    const float* context = (const float*)d_in[1];
    const float* gx = (const float*)d_in[4];
    const float* bx = (const float*)d_in[5];
    const float* gc = (const float*)d_in[6];
    const float* bc = (const float*)d_in[7];
    const float* w_qk = (const float*)d_in[8];
    const float* w_cqk = (const float*)d_in[9];
    const float* w_v = (const float*)d_in[10];
    const float* w_cv = (const float*)d_in[11];
    const float* w_out = (const float*)d_in[12];
    const float* b_out = (const float*)d_in[13];
    const float* w_cout = (const float*)d_in[14];
    const float* b_cout = (const float*)d_in[15];
    const float* w_th = (const float*)d_in[16];
    const float* w_cth = (const float*)d_in[17];
    const float* ffg = (const float*)d_in[18];
    const float* ffb = (const float*)d_in[19];
    const float* ffw1 = (const float*)d_in[20];
    const float* ffb1 = (const float*)d_in[21];
    const float* ffw2 = (const float*)d_in[22];
    const float* ffb2 = (const float*)d_in[23];
    const float* cffg = (const float*)d_in[24];
    const float* cffb = (const float*)d_in[25];
    const float* cffw1 = (const float*)d_in[26];
    const float* cffb1 = (const float*)d_in[27];
    const float* cffw2 = (const float*)d_in[28];
    const float* cffb2 = (const float*)d_in[29];

    const long long TOK = (long long)BB * NN;   // 4096

    // ---- workspace layout (~180 MB) ----
    bf16* xn = (bf16*)d_ws;                       // 4 M elems
    bf16* cn = xn + TOK * DIMD;                   // 4 M (right after xn: AHALF)
    bf16* qk = cn + TOK * DIMD;                   // 2 M each, order qk,vv,cqk,cv
    bf16* vv = qk + TOK * INNERD;
    bf16* cqk = vv + TOK * INNERD;
    bf16* cv = cqk + TOK * INNERD;
    bf16* outb = cv + TOK * INNERD;               // [B][2][NN][INNERD] = 4 M
    bf16* sim = outb + (long long)BB * 2 * NN * INNERD;  // 32 M (8 planes)
    bf16* w4 = sim + (long long)HH * NM;          // 32 M: simT during attention;
    bf16* ffw1T = w4;                             //   then ffw1T,cffw1T,ffw2T,cffw2T
    bf16* cffw1T = ffw1T + (long long)FFD * DIMD;
    bf16* ffw2T = cffw1T + (long long)FFD * DIMD;
    bf16* cffw2T = ffw2T + (long long)DIMD * FFD;
    bf16* simT = w4;                              // alias (attention phase only)
    bf16* wqkT = w4 + 4LL * FFD * DIMD;           // 0.5 M each, order for proj z
    bf16* wvT = wqkT + (long long)INNERD * DIMD;
    bf16* wcqkT = wvT + (long long)INNERD * DIMD;
    bf16* wcvT = wcqkT + (long long)INNERD * DIMD;
    bf16* woutT = wcvT + (long long)INNERD * DIMD;
    bf16* wcoutT = woutT + (long long)DIMD * INNERD;
    bf16* cvT = wcoutT + (long long)DIMD * INNERD;  // order cvT then vT for pv z-map
    bf16* vT = cvT + (long long)INNERD * NN;
    float* stats = (float*)(vT + (long long)INNERD * NN);
    float* mc = stats;                 // 8*2048
    float* lc = mc + HH * MM;
    float* mcp = lc + HH * MM;         // 8*8*2048
    float* lcp = mcp + 8 * HH * MM;

    float* out_x = (float*)d_out;
    float* out_c = out_x + TOK * DIMD;

    dim3 blk(256);

    // --- small weight transposes (proj + out-proj) ---
    transpose_k<float><<<dim3(INNERD / 32, DIMD / 32), blk, 0, stream>>>(w_qk, wqkT, DIMD, INNERD);
    transpose_k<float><<<dim3(INNERD / 32, DIMD / 32), blk, 0, stream>>>(w_v, wvT, DIMD, INNERD);
    transpose_k<float><<<dim3(INNERD / 32, DIMD / 32), blk, 0, stream>>>(w_cqk, wcqkT, DIMD, INNERD);
    transpose_k<float><<<dim3(INNERD / 32, DIMD / 32), blk, 0, stream>>>(w_cv, wcvT, DIMD, INNERD);
    transpose_k<float><<<dim3(DIMD / 32, INNERD / 32), blk, 0, stream>>>(w_out, woutT, INNERD, DIMD);
    transpose_k<float><<<dim3(DIMD / 32, INNERD / 32), blk, 0, stream>>>(w_cout, wcoutT, INNERD, DIMD);

    // --- input layernorms ---
    layernorm_k<<<TOK, blk, 0, stream>>>(x, xn, gx, bx);
    layernorm_k<<<TOK, blk, 0, stream>>>(context, cn, gc, bc);

    // --- all 4 projections in one launch (z=4, AHALF) ---
    {
        dim3 g(INNERD / 128, TOK / 128, 4);
        mgemm<128, 128, 2, 1, false, bf16><<<g, blk, 0, stream>>>(xn, wqkT, qk,
            DIMD, DIMD, DIMD, INNERD,
            TOK * DIMD, (long long)INNERD * DIMD, TOK * INNERD,
            1.f, nullptr, nullptr, nullptr, nullptr, 0, 0);
    }

    // --- attention, per batch ---
    for (int b = 0; b < BB; b++) {
        const bf16* qk_b = qk + (long long)b * NN * INNERD;
        const bf16* cqk_b = cqk + (long long)b * NN * INNERD;
        const bf16* v_b = vv + (long long)b * NN * INNERD;
        const bf16* cv_b = cv + (long long)b * NN * INNERD;
        bf16* outb_b = outb + (long long)b * 2 * NN * INNERD;

        transpose_k<bf16><<<dim3(INNERD / 32, NN / 32), blk, 0, stream>>>(cv_b, cvT, NN, INNERD);
        transpose_k<bf16><<<dim3(INNERD / 32, NN / 32), blk, 0, stream>>>(v_b, vT, NN, INNERD);

        // sim[h,i,j] = SCALE * qk_h[i,:] . cqk_h[j,:]
        {
            dim3 gs(MM / 128, NN / 128, HH);
            mgemm<128, 128, 2, 0, false, bf16><<<gs, blk, 0, stream>>>(qk_b, cqk_b, sim,
                DHD, INNERD, INNERD, MM, DHD, DHD, NM,
                SCALE_QK, nullptr, nullptr, nullptr, nullptr, 0, 0);
        }
        // column stats from pristine sim
        {
            dim3 g(MM / 256, HH, 8);
            colstats_part_k<<<g, blk, 0, stream>>>(sim, mcp, lcp);
        }
        colstats_comb_k<<<HH * MM / 256, blk, 0, stream>>>(mcp, lcp, mc, lc);
        // col path -> simT (transposed+mixed), then row path in place
        mixcolT_k<<<dim3(MM / 32, NN / 32), blk, 0, stream>>>(sim, simT, w_cth, mc, lc);
        rowsoftmix_k<<<NN, blk, 0, stream>>>(sim, w_th);
        // both P@V products, one launch (z=16)
        pv_k<<<dim3(1, NN / 64, 16), blk, 0, stream>>>(sim, cvT, outb_b);
    }

    // --- out-projections, one launch (z=2, ROWGAP) + bias + residual -> d_out ---
    {
        dim3 g(DIMD / 128, TOK / 128, 2);
        mgemm<128, 128, 2, 2, false, float><<<g, blk, 0, stream>>>(outb, woutT, out_x,
            INNERD, INNERD, INNERD, DIMD,
            0, (long long)DIMD * INNERD, TOK * DIMD,
            1.f, b_out, b_cout, x, context, DIMD, 0);
    }

    // --- FFN weight transposes (w4 region now free) ---
    transpose_k<float><<<dim3(FFD / 32, DIMD / 32), blk, 0, stream>>>(ffw1, ffw1T, DIMD, FFD);
    transpose_k<float><<<dim3(FFD / 32, DIMD / 32), blk, 0, stream>>>(cffw1, cffw1T, DIMD, FFD);
    transpose_k<float><<<dim3(DIMD / 32, FFD / 32), blk, 0, stream>>>(ffw2, ffw2T, FFD, DIMD);
    transpose_k<float><<<dim3(DIMD / 32, FFD / 32), blk, 0, stream>>>(cffw2, cffw2T, FFD, DIMD);

    // --- FFN per model: LN -> bias-preadd -> 256^2 8-phase GEMM1(+gelu)
    //     -> 256^2 8-phase split-K GEMM2 (atomic) ---
    const float* g_[2] = {ffg, cffg};
    const float* bterm_[2] = {ffb, cffb};
    const float* b1_[2] = {ffb1, cffb1};
    const float* b2_[2] = {ffb2, cffb2};
    const bf16* w1T_[2] = {ffw1T, cffw1T};
    const bf16* w2T_[2] = {ffw2T, cffw2T};
    float* outp_[2] = {out_x, out_c};
    bf16* lnb = xn;
    bf16* hid = sim;  // [4096][8192]
    for (int m = 0; m < 2; m++) {
        layernorm_k<<<TOK, blk, 0, stream>>>(outp_[m], lnb, g_[m], bterm_[m]);
        biasadd_k<<<TOK * DIMD / 1024, blk, 0, stream>>>(outp_[m], b2_[m]);
        {
            // GEMM1: [4096x1024] @ [1024x8192]^T -> gelu -> hid (bf16)
            dim3 g(FFD / 256, TOK / 256, 1);  // 32 x 16 = 512 wg (nwg%8==0)
            mgemm256<true, false, bf16><<<g, dim3(512), 0, stream>>>(lnb, w1T_[m], hid,
                DIMD, DIMD, DIMD, FFD, 0, 0, 0, b1_[m]);
        }
        {
            // GEMM2: split-K=4 (z offsets A,B by z*2048 in k); atomicAdd into d_out
            dim3 g(DIMD / 256, TOK / 256, 4);  // 4 x 16 x 4 = 256 wg (1/CU exactly)
            mgemm256<false, true, float><<<g, dim3(512), 0, stream>>>(hid, w2T_[m], outp_[m],
                FFD / 4, FFD, FFD, DIMD, 2048, 2048, 0, nullptr);
        }
    }
}

// Round 2
// 1195.891 us; speedup vs baseline: 1.2991x; 1.2196x over previous
//
#include <hip/hip_runtime.h>
#include <hip/hip_bf16.h>
#include <math.h>

#define BB 2
#define NN 2048
#define MM 2048
#define DIMD 1024
#define HH 8
#define DHD 64
#define INNERD 512
#define FFD 8192
#define SCALE_QK 0.125f
#define LOG2E 1.44269504088896f

typedef __hip_bfloat16 bf16;
typedef float f32x4 __attribute__((ext_vector_type(4)));
typedef short short8 __attribute__((ext_vector_type(8)));
static const long long NM = (long long)NN * MM;

__device__ __forceinline__ float cvt(float v) { return v; }
__device__ __forceinline__ float cvt(bf16 v) { return __bfloat162float(v); }
__device__ __forceinline__ void stc(float* p, float v) { *p = v; }
__device__ __forceinline__ void stc(bf16* p, float v) { *p = __float2bfloat16(v); }

__device__ __forceinline__ float bits2f(short u) {
    return __uint_as_float(((unsigned)(unsigned short)u) << 16);
}
__device__ __forceinline__ short bf16bits(float f) {
    bf16 t = __float2bfloat16(f);
    short s;
    __builtin_memcpy(&s, &t, 2);
    return s;
}

__device__ __forceinline__ void gl_lds16(const bf16* g, bf16* l) {
    __builtin_amdgcn_global_load_lds(
        (const __attribute__((address_space(1))) void*)(g),
        (__attribute__((address_space(3))) void*)(l), 16, 0, 0);
}

// ---------------- reductions ----------------
__device__ __forceinline__ float block_reduce_sum(float v) {
    __shared__ float sh[4];
    int tid = threadIdx.x;
#pragma unroll
    for (int off = 32; off > 0; off >>= 1) v += __shfl_down(v, off, 64);
    __syncthreads();
    if ((tid & 63) == 0) sh[tid >> 6] = v;
    __syncthreads();
    return sh[0] + sh[1] + sh[2] + sh[3];
}

// ---------------- layernorm: fp32 in -> bf16 out ----------------
__global__ __launch_bounds__(256) void layernorm_k(const float* __restrict__ in,
                                                   bf16* __restrict__ out,
                                                   const float* __restrict__ g,
                                                   const float* __restrict__ b) {
    long long row = blockIdx.x;
    const float* xr = in + row * DIMD;
    bf16* yr = out + row * DIMD;
    int tid = threadIdx.x;
    float s = 0.f;
    for (int i = tid; i < DIMD; i += 256) s += xr[i];
    float mean = block_reduce_sum(s) * (1.0f / DIMD);
    float s2 = 0.f;
    for (int i = tid; i < DIMD; i += 256) { float d = xr[i] - mean; s2 += d * d; }
    float var = block_reduce_sum(s2) * (1.0f / DIMD);
    float inv = 1.0f / sqrtf(var + 1e-5f);
    for (int i = tid; i < DIMD; i += 256)
        yr[i] = __float2bfloat16((xr[i] - mean) * inv * g[i] + b[i]);
}

// ---------------- bias add (fp32, vectorized) ----------------
__global__ __launch_bounds__(256) void biasadd_k(float* __restrict__ out,
                                                 const float* __restrict__ bias) {
    long long idx = (long long)blockIdx.x * 256 + threadIdx.x;  // float4 index
    f32x4 v = ((f32x4*)out)[idx];
    const f32x4 bv = ((const f32x4*)bias)[idx & (DIMD / 4 - 1)];
    v.x += bv.x; v.y += bv.y; v.z += bv.z; v.w += bv.w;
    ((f32x4*)out)[idx] = v;
}

// ---------------- transpose + convert: in [R][C] -> out bf16 [C][R] ----------------
template <typename TI>
__global__ __launch_bounds__(256) void transpose_k(const TI* __restrict__ in,
                                                   bf16* __restrict__ out,
                                                   int R, int C) {
    __shared__ bf16 t[32][33];
    int bc = blockIdx.x * 32, br = blockIdx.y * 32;
    int tid = threadIdx.x;
    int c = tid & 31, r0 = tid >> 5;
#pragma unroll
    for (int s = 0; s < 4; s++) {
        int r = r0 + s * 8;
        t[r][c] = __float2bfloat16(cvt(in[(long long)(br + r) * C + bc + c]));
    }
    __syncthreads();
#pragma unroll
    for (int s = 0; s < 4; s++) {
        int r = r0 + s * 8;
        out[(long long)(bc + r) * R + br + c] = t[c][r];
    }
}

// ---------------- col softmax stats over i: partial (two-pass) then combine ----------------
// 16 chunks of 128 rows each. exp base-2 everywhere (consistent with comb + mixcolT).
__global__ __launch_bounds__(256) void colstats_part_k(const bf16* __restrict__ sim,
                                                       float* __restrict__ mcp,
                                                       float* __restrict__ lcp) {
    int j = blockIdx.x * 256 + threadIdx.x;
    int h = blockIdx.y;
    int ic = blockIdx.z;
    const bf16* base = sim + (long long)h * NM + (long long)ic * 128 * MM + j;
    float m = -3.4e38f;
#pragma unroll 8
    for (int i = 0; i < 128; i++) m = fmaxf(m, cvt(base[(long long)i * MM]));
    float s = 0.f;
#pragma unroll 8
    for (int i = 0; i < 128; i++)
        s += exp2f((cvt(base[(long long)i * MM]) - m) * LOG2E);
    mcp[((long long)ic * HH + h) * MM + j] = m;
    lcp[((long long)ic * HH + h) * MM + j] = s;
}

__global__ __launch_bounds__(256) void colstats_comb_k(const float* __restrict__ mcp,
                                                       const float* __restrict__ lcp,
                                                       float* __restrict__ mc,
                                                       float* __restrict__ lc) {
    int idx = blockIdx.x * 256 + threadIdx.x;  // h*MM + j
    int h = idx >> 11, j = idx & (MM - 1);
    float m = -3.4e38f;
#pragma unroll
    for (int ic = 0; ic < 16; ic++) m = fmaxf(m, mcp[((long long)ic * HH + h) * MM + j]);
    float l = 0.f;
#pragma unroll
    for (int ic = 0; ic < 16; ic++)
        l += lcp[((long long)ic * HH + h) * MM + j] *
             exp2f((mcp[((long long)ic * HH + h) * MM + j] - m) * LOG2E);
    mc[idx] = m;
    lc[idx] = l;
}

// ---------------- col path: normalize + mix + transpose, sim -> simT ----------------
// Tile 64 rows (i) x 32 cols (j). short8 loads -> XOR-swizzled LDS -> short8 stores.
// LDS layout per plane h: 64 rows x 64B; row il, 16B slot s stored at slot (s ^ ((il>>3)&3)).
__global__ __launch_bounds__(256) void mixcolT_k(const bf16* __restrict__ sim,
                                                 bf16* __restrict__ simT,
                                                 const float* __restrict__ w,
                                                 const float* __restrict__ mc,
                                                 const float* __restrict__ lc) {
    __shared__ __align__(16) bf16 t[HH * 64 * 32];
    __shared__ float ws_[64];
    int j0 = blockIdx.x * 32, i0 = blockIdx.y * 64;
    int tid = threadIdx.x;
    if (tid < 64) ws_[tid] = w[tid];
#pragma unroll
    for (int q = 0; q < 8; q++) {
        int c = q * 256 + tid;  // [h(8)][r(64)][jc(4)]
        int h = c >> 8, r = (c >> 2) & 63, jc = c & 3;
        short8 x = *(const short8*)&sim[(long long)h * NM + (long long)(i0 + r) * MM + j0 + jc * 8];
        *(short8*)&t[h * 2048 + r * 32 + (jc ^ ((r >> 3) & 3)) * 8] = x;
    }
    __syncthreads();
    int jl = tid >> 3, io = tid & 7;
    int jg = j0 + jl;
    float e[HH][8];
#pragma unroll
    for (int h = 0; h < HH; h++) {
        float mcj = mc[h * MM + jg];
        float rl = 1.0f / lc[h * MM + jg];
#pragma unroll
        for (int k = 0; k < 8; k++) {
            int il = io * 8 + k;
            float v = cvt(t[h * 2048 + il * 32 + (((jl >> 3) ^ io) & 3) * 8 + (jl & 7)]);
            e[h][k] = exp2f((v - mcj) * LOG2E) * rl;
        }
    }
#pragma unroll
    for (int g = 0; g < HH; g++) {
        short8 o;
#pragma unroll
        for (int k = 0; k < 8; k++) {
            float acc = 0.f;
#pragma unroll
            for (int h = 0; h < HH; h++) acc += ws_[g * 8 + h] * e[h][k];
            o[k] = bf16bits(acc);
        }
        *(short8*)&simT[(long long)g * NM + (long long)jg * MM + i0 + io * 8] = o;
    }
}

// ---------------- row path: fused row-stats + normalize + mix, in place ----------------
// Vectorized: short8 loads/stores, butterfly shfl reductions, exp2 computed once.
__global__ __launch_bounds__(256) void rowsoftmix_k(bf16* __restrict__ sim,
                                                    const float* __restrict__ w) {
    __shared__ float ws_[64];
    __shared__ float redm[HH][4];
    __shared__ float redl[HH][4];
    long long i = blockIdx.x;
    int tid = threadIdx.x, lane = tid & 63, wv = tid >> 6;
    if (tid < 64) ws_[tid] = w[tid];
    bf16* rowbase = sim + i * MM + tid * 8;
    float v[HH][8];
#pragma unroll
    for (int h = 0; h < HH; h++) {
        short8 r = *(const short8*)(rowbase + (long long)h * NM);
#pragma unroll
        for (int c = 0; c < 8; c++) v[h][c] = bits2f(r[c]);
    }
    float mh[HH];
#pragma unroll
    for (int h = 0; h < HH; h++) {
        float m = fmaxf(fmaxf(fmaxf(v[h][0], v[h][1]), fmaxf(v[h][2], v[h][3])),
                        fmaxf(fmaxf(v[h][4], v[h][5]), fmaxf(v[h][6], v[h][7])));
#pragma unroll
        for (int off = 32; off > 0; off >>= 1) m = fmaxf(m, __shfl_xor(m, off, 64));
        if (lane == 0) redm[h][wv] = m;
    }
    __syncthreads();
#pragma unroll
    for (int h = 0; h < HH; h++)
        mh[h] = fmaxf(fmaxf(redm[h][0], redm[h][1]), fmaxf(redm[h][2], redm[h][3]));
#pragma unroll
    for (int h = 0; h < HH; h++) {
        float s = 0.f;
#pragma unroll
        for (int c = 0; c < 8; c++) {
            v[h][c] = exp2f((v[h][c] - mh[h]) * LOG2E);
            s += v[h][c];
        }
#pragma unroll
        for (int off = 32; off > 0; off >>= 1) s += __shfl_xor(s, off, 64);
        if (lane == 0) redl[h][wv] = s;
    }
    __syncthreads();
#pragma unroll
    for (int h = 0; h < HH; h++) {
        float inv = 1.0f / (redl[h][0] + redl[h][1] + redl[h][2] + redl[h][3]);
#pragma unroll
        for (int c = 0; c < 8; c++) v[h][c] *= inv;
    }
#pragma unroll
    for (int g = 0; g < HH; g++) {
        short8 o;
#pragma unroll
        for (int c = 0; c < 8; c++) {
            float acc = 0.f;
#pragma unroll
            for (int h = 0; h < HH; h++) acc += ws_[g * 8 + h] * v[h][c];
            o[c] = bf16bits(acc);
        }
        *(short8*)(rowbase + (long long)g * NM) = o;
    }
}

// ---------------- MFMA bf16 GEMM (128^2, 2-barrier; kept for small/odd shapes) ----------------
// C[m,n] = alpha * sum_k A[m][k] * B[n][k]  (+bias[n]) (+residual[m,n]) (->gelu)
template <int BM, int BN, int WROWS, int ZMODE, bool ATOMIC, typename CT>
__global__ __launch_bounds__(256) void mgemm(
    const bf16* __restrict__ A, const bf16* __restrict__ B, CT* __restrict__ C,
    int K, int lda, int ldb, int ldc,
    long long sA, long long sB, long long sC,
    float alpha, const float* __restrict__ bias, const float* __restrict__ bias2,
    const float* __restrict__ residual, const float* __restrict__ residual2,
    int ldr, int gelu_flag) {
    constexpr int BK = 32;
    constexpr int WCOLS = 4 / WROWS;
    constexpr int WM = BM / WROWS, WN = BN / WCOLS;
    constexpr int FM = WM / 16, FN = WN / 16;
    constexpr int ACH = BM * BK / 8;
    constexpr int BCH = BN * BK / 8;
    __shared__ bf16 As[BM * BK];
    __shared__ bf16 Bs[BN * BK];
    int z = blockIdx.z;
    int m0 = blockIdx.y * BM, n0 = blockIdx.x * BN;
    if (ZMODE == 0) A += z * sA;
    else if (ZMODE == 1) A += (long long)(z >> 1) * sA;
    else if (ZMODE == 2) A += ((long long)(((m0 >> 11) << 1) + z) * 2048 - m0) * lda;
    B += z * sB;
    C += z * sC;
    const float* bb_ = bias;
    const float* rr_ = residual;
    if (ZMODE == 2 && z) { bb_ = bias2; rr_ = residual2; }
    int tid = threadIdx.x, lane = tid & 63, w = tid >> 6;
    int wm = (w / WCOLS) * WM, wn = (w % WCOLS) * WN;
    f32x4 acc[FM][FN] = {};
    for (int k0 = 0; k0 < K; k0 += BK) {
        __syncthreads();
#pragma unroll
        for (int c = tid; c < ACH; c += 256) {
            int row = c >> 2, col = (c & 3) * 8;
            gl_lds16(A + (long long)(m0 + row) * lda + k0 + col, As + c * 8);
        }
#pragma unroll
        for (int c = tid; c < BCH; c += 256) {
            int row = c >> 2, col = (c & 3) * 8;
            gl_lds16(B + (long long)(n0 + row) * ldb + k0 + col, Bs + c * 8);
        }
        __syncthreads();
        short8 af[FM], bfr[FN];
#pragma unroll
        for (int fm = 0; fm < FM; fm++)
            af[fm] = *(const short8*)&As[(wm + fm * 16 + (lane & 15)) * BK + (lane >> 4) * 8];
#pragma unroll
        for (int fn = 0; fn < FN; fn++)
            bfr[fn] = *(const short8*)&Bs[(wn + fn * 16 + (lane & 15)) * BK + (lane >> 4) * 8];
#pragma unroll
        for (int fm = 0; fm < FM; fm++)
#pragma unroll
            for (int fn = 0; fn < FN; fn++)
                acc[fm][fn] = __builtin_amdgcn_mfma_f32_16x16x32_bf16(af[fm], bfr[fn], acc[fm][fn], 0, 0, 0);
    }
#pragma unroll
    for (int fm = 0; fm < FM; fm++) {
#pragma unroll
        for (int fn = 0; fn < FN; fn++) {
#pragma unroll
            for (int r = 0; r < 4; r++) {
                int m = m0 + wm + fm * 16 + (lane >> 4) * 4 + r;
                int n = n0 + wn + fn * 16 + (lane & 15);
                float v = acc[fm][fn][r] * alpha;
                if (bb_) v += bb_[n];
                if (rr_) v += rr_[(long long)m * ldr + n];
                if (gelu_flag) v = 0.5f * v * (1.0f + erff(v * 0.70710678118654752440f));
                if (ATOMIC) atomicAdd((float*)&C[(long long)m * ldc + n], v);
                else stc(&C[(long long)m * ldc + n], v);
            }
        }
    }
}

// ---------------- 256x256 8-phase MFMA GEMM (T2+T3+T4+T5) ----------------
template <bool GELU, bool ATOMIC, typename CT>
__global__ __launch_bounds__(512, 2) void mgemm256(
    const bf16* __restrict__ A, const bf16* __restrict__ B, CT* __restrict__ C,
    int K, int lda, int ldb, int ldc,
    long long sA, long long sB, long long sC,
    const float* __restrict__ bias) {
    __shared__ bf16 sm[65536];
    const int T = K >> 6;  // K-tiles of 64
    int z = blockIdx.z;
    A += (long long)z * sA;
    B += (long long)z * sB;
    C += (long long)z * sC;
    int gx = gridDim.x;
    int nwg = gx * gridDim.y;
    int id = blockIdx.y * gx + blockIdx.x;
    id = (id & 7) * (nwg >> 3) + (id >> 3);
    int n0 = (id % gx) * 256;
    int m0 = (id / gx) * 256;

    int tid = threadIdx.x, lane = tid & 63, w = tid >> 6;
    int wrow = w >> 2, wcol = w & 3;
    int sr = tid >> 3;                       // 0..63
    int ecol = (((tid >> 3) ^ tid) & 7) * 8; // pre-swizzled global col (elements)

    auto stage = [&](const bf16* g, int ld, int row0, int k0, bf16* l) {
        const bf16* s = g + (long long)(row0 + sr) * ld + k0 + ecol;
        gl_lds16(s, l + (tid << 3));
        gl_lds16(s + (long long)(ld << 6), l + 4096 + (tid << 3));
    };

    f32x4 acc[8][4] = {};

    stage(A, lda, m0, 0, sm);
    stage(A, lda, m0 + 128, 0, sm + 8192);
    stage(B, ldb, n0, 0, sm + 32768);
    stage(B, ldb, n0 + 128, 0, sm + 32768 + 8192);
    if (T > 1) {
        stage(B, ldb, n0, 64, sm + 32768 + 16384);
        stage(B, ldb, n0 + 128, 64, sm + 32768 + 16384 + 8192);
        asm volatile("s_waitcnt vmcnt(4)" ::: "memory");
    } else {
        asm volatile("s_waitcnt vmcnt(0)" ::: "memory");
    }
    __builtin_amdgcn_s_barrier();

    for (int kt = 0; kt < T; ++kt) {
        const int cur = kt & 1, nxt = cur ^ 1;
        const bf16* Ab = sm + cur * 16384;
        const bf16* Bb = sm + 32768 + cur * 16384;
        short8 bf_[4][2];
#pragma unroll
        for (int fn = 0; fn < 4; fn++)
#pragma unroll
            for (int kk = 0; kk < 2; kk++) {
                int row = wcol * 64 + fn * 16 + (lane & 15);
                int cb = (kk * 64 + ((lane >> 4) << 4)) ^ ((row & 7) << 4);
                bf_[fn][kk] = *(const short8*)((const char*)Bb + row * 128 + cb);
            }
#pragma unroll
        for (int q = 0; q < 4; q++) {
            short8 af[2][2];
#pragma unroll
            for (int i = 0; i < 2; i++)
#pragma unroll
                for (int kk = 0; kk < 2; kk++) {
                    int row = wrow * 128 + (q * 2 + i) * 16 + (lane & 15);
                    int cb = (kk * 64 + ((lane >> 4) << 4)) ^ ((row & 7) << 4);
                    af[i][kk] = *(const short8*)((const char*)Ab + row * 128 + cb);
                }
            if (q == 0) {
                if (kt + 1 < T) stage(A, lda, m0, (kt + 1) << 6, sm + nxt * 16384);
            } else if (q == 1) {
                if (kt + 1 < T) stage(A, lda, m0 + 128, (kt + 1) << 6, sm + nxt * 16384 + 8192);
            } else if (q == 2) {
                if (kt + 2 < T) stage(B, ldb, n0, (kt + 2) << 6, sm + 32768 + cur * 16384);
            } else {
                if (kt + 2 < T) {
                    stage(B, ldb, n0 + 128, (kt + 2) << 6, sm + 32768 + cur * 16384 + 8192);
                    asm volatile("s_waitcnt vmcnt(4)" ::: "memory");
                } else {
                    asm volatile("s_waitcnt vmcnt(0)" ::: "memory");
                }
            }
            __builtin_amdgcn_s_barrier();
            __builtin_amdgcn_s_setprio(1);
#pragma unroll
            for (int i = 0; i < 2; i++)
#pragma unroll
                for (int fn = 0; fn < 4; fn++)
#pragma unroll
                    for (int kk = 0; kk < 2; kk++)
                        acc[q * 2 + i][fn] = __builtin_amdgcn_mfma_f32_16x16x32_bf16(
                            af[i][kk], bf_[fn][kk], acc[q * 2 + i][fn], 0, 0, 0);
            __builtin_amdgcn_s_setprio(0);
            __builtin_amdgcn_s_barrier();
        }
    }

    long long crow0 = m0 + wrow * 128 + ((lane >> 4) << 2);
    int ccol0 = n0 + wcol * 64 + (lane & 15);
#pragma unroll
    for (int fm = 0; fm < 8; fm++)
#pragma unroll
        for (int fn = 0; fn < 4; fn++)
#pragma unroll
            for (int r = 0; r < 4; r++) {
                long long m = crow0 + fm * 16 + r;
                int n = ccol0 + fn * 16;
                float v = acc[fm][fn][r];
                if (bias) v += bias[n];
                if (GELU) v = 0.5f * v * (1.0f + erff(v * 0.70710678118654752440f));
                if (ATOMIC) atomicAdd((float*)&C[m * ldc + n], v);
                else stc(&C[m * ldc + n], v);
            }
}

// ---------------- attention P@V, both paths in one launch ----------------
__global__ __launch_bounds__(256) void pv_k(const bf16* __restrict__ P,
                                            const bf16* __restrict__ Vt,
                                            bf16* __restrict__ O) {
    constexpr int BK = 32;
    __shared__ bf16 As[64 * BK];
    __shared__ bf16 Bs[64 * BK];
    int z = blockIdx.z;
    int h = z & 7, sel = z >> 3;
    const bf16* A = P + (long long)z * NM;
    const bf16* B = Vt + (long long)z * DHD * NN;
    bf16* C = O + (long long)sel * NN * INNERD + h * DHD;
    int m0 = blockIdx.y * 64;
    int tid = threadIdx.x, lane = tid & 63, w = tid >> 6;
    int wm = w * 16;
    f32x4 acc[4] = {};
    for (int k0 = 0; k0 < NN; k0 += BK) {
        __syncthreads();
        {
            int row = tid >> 2, col = (tid & 3) * 8;
            gl_lds16(A + (long long)(m0 + row) * MM + k0 + col, As + tid * 8);
            gl_lds16(B + (long long)row * NN + k0 + col, Bs + tid * 8);
        }
        __syncthreads();
        short8 af = *(const short8*)&As[(wm + (lane & 15)) * BK + (lane >> 4) * 8];
#pragma unroll
        for (int fn = 0; fn < 4; fn++) {
            short8 bfr = *(const short8*)&Bs[(fn * 16 + (lane & 15)) * BK + (lane >> 4) * 8];
            acc[fn] = __builtin_amdgcn_mfma_f32_16x16x32_bf16(af, bfr, acc[fn], 0, 0, 0);
        }
    }
#pragma unroll
    for (int fn = 0; fn < 4; fn++)
#pragma unroll
        for (int r = 0; r < 4; r++) {
            int m = m0 + wm + (lane >> 4) * 4 + r;
            int n = fn * 16 + (lane & 15);
            stc(&C[(long long)m * INNERD + n], acc[fn][r]);
        }
}

extern "C" void kernel_launch(void* const* d_in, const int* in_sizes, int n_in,
                              void* d_out, int out_size, void* d_ws, size_t ws_size,
                              hipStream_t stream) {
    const float* x = (const float*)d_in[0];
    const float* context = (const float*)d_in[1];
    const float* gx = (const float*)d_in[4];
    const float* bx = (const float*)d_in[5];
    const float* gc = (const float*)d_in[6];
    const float* bc = (const float*)d_in[7];
    const float* w_qk = (const float*)d_in[8];
    const float* w_cqk = (const float*)d_in[9];
    const float* w_v = (const float*)d_in[10];
    const float* w_cv = (const float*)d_in[11];
    const float* w_out = (const float*)d_in[12];
    const float* b_out = (const float*)d_in[13];
    const float* w_cout = (const float*)d_in[14];
    const float* b_cout = (const float*)d_in[15];
    const float* w_th = (const float*)d_in[16];
    const float* w_cth = (const float*)d_in[17];
    const float* ffg = (const float*)d_in[18];
    const float* ffb = (const float*)d_in[19];
    const float* ffw1 = (const float*)d_in[20];
    const float* ffb1 = (const float*)d_in[21];
    const float* ffw2 = (const float*)d_in[22];
    const float* ffb2 = (const float*)d_in[23];
    const float* cffg = (const float*)d_in[24];
    const float* cffb = (const float*)d_in[25];
    const float* cffw1 = (const float*)d_in[26];
    const float* cffb1 = (const float*)d_in[27];
    const float* cffw2 = (const float*)d_in[28];
    const float* cffb2 = (const float*)d_in[29];

    const long long TOK = (long long)BB * NN;   // 4096

    // ---- workspace layout ----
    bf16* xn = (bf16*)d_ws;                       // 4 M elems
    bf16* cn = xn + TOK * DIMD;                   // 4 M (right after xn: AHALF)
    bf16* qk = cn + TOK * DIMD;                   // 2 M each, order qk,vv,cqk,cv
    bf16* vv = qk + TOK * INNERD;
    bf16* cqk = vv + TOK * INNERD;
    bf16* cv = cqk + TOK * INNERD;
    bf16* outb = cv + TOK * INNERD;               // [B][2][NN][INNERD] = 4 M
    bf16* sim = outb + (long long)BB * 2 * NN * INNERD;  // 32 M (8 planes)
    bf16* w4 = sim + (long long)HH * NM;          // 32 M: simT during attention;
    bf16* ffw1T = w4;                             //   then ffw1T,cffw1T,ffw2T,cffw2T
    bf16* cffw1T = ffw1T + (long long)FFD * DIMD;
    bf16* ffw2T = cffw1T + (long long)FFD * DIMD;
    bf16* cffw2T = ffw2T + (long long)DIMD * FFD;
    bf16* simT = w4;                              // alias (attention phase only)
    bf16* wqkT = w4 + 4LL * FFD * DIMD;           // 0.5 M each, order for proj z
    bf16* wvT = wqkT + (long long)INNERD * DIMD;
    bf16* wcqkT = wvT + (long long)INNERD * DIMD;
    bf16* wcvT = wcqkT + (long long)INNERD * DIMD;
    bf16* woutT = wcvT + (long long)INNERD * DIMD;
    bf16* wcoutT = woutT + (long long)DIMD * INNERD;
    bf16* cvT = wcoutT + (long long)DIMD * INNERD;  // order cvT then vT for pv z-map
    bf16* vT = cvT + (long long)INNERD * NN;
    float* stats = (float*)(vT + (long long)INNERD * NN);
    float* mc = stats;                 // 8*2048
    float* lc = mc + HH * MM;
    float* mcp = lc + HH * MM;         // 16*8*2048
    float* lcp = mcp + 16 * HH * MM;

    float* out_x = (float*)d_out;
    float* out_c = out_x + TOK * DIMD;

    dim3 blk(256);

    // --- small weight transposes (proj + out-proj) ---
    transpose_k<float><<<dim3(INNERD / 32, DIMD / 32), blk, 0, stream>>>(w_qk, wqkT, DIMD, INNERD);
    transpose_k<float><<<dim3(INNERD / 32, DIMD / 32), blk, 0, stream>>>(w_v, wvT, DIMD, INNERD);
    transpose_k<float><<<dim3(INNERD / 32, DIMD / 32), blk, 0, stream>>>(w_cqk, wcqkT, DIMD, INNERD);
    transpose_k<float><<<dim3(INNERD / 32, DIMD / 32), blk, 0, stream>>>(w_cv, wcvT, DIMD, INNERD);
    transpose_k<float><<<dim3(DIMD / 32, INNERD / 32), blk, 0, stream>>>(w_out, woutT, INNERD, DIMD);
    transpose_k<float><<<dim3(DIMD / 32, INNERD / 32), blk, 0, stream>>>(w_cout, wcoutT, INNERD, DIMD);

    // --- input layernorms ---
    layernorm_k<<<TOK, blk, 0, stream>>>(x, xn, gx, bx);
    layernorm_k<<<TOK, blk, 0, stream>>>(context, cn, gc, bc);

    // --- all 4 projections in one launch (z=4, AHALF) ---
    {
        dim3 g(INNERD / 128, TOK / 128, 4);
        mgemm<128, 128, 2, 1, false, bf16><<<g, blk, 0, stream>>>(xn, wqkT, qk,
            DIMD, DIMD, DIMD, INNERD,
            TOK * DIMD, (long long)INNERD * DIMD, TOK * INNERD,
            1.f, nullptr, nullptr, nullptr, nullptr, 0, 0);
    }

    // --- attention, per batch ---
    for (int b = 0; b < BB; b++) {
        const bf16* qk_b = qk + (long long)b * NN * INNERD;
        const bf16* cqk_b = cqk + (long long)b * NN * INNERD;
        const bf16* v_b = vv + (long long)b * NN * INNERD;
        const bf16* cv_b = cv + (long long)b * NN * INNERD;
        bf16* outb_b = outb + (long long)b * 2 * NN * INNERD;

        transpose_k<bf16><<<dim3(INNERD / 32, NN / 32), blk, 0, stream>>>(cv_b, cvT, NN, INNERD);
        transpose_k<bf16><<<dim3(INNERD / 32, NN / 32), blk, 0, stream>>>(v_b, vT, NN, INNERD);

        // sim[h,i,j] = SCALE * qk_h[i,:] . cqk_h[j,:]
        {
            dim3 gs(MM / 128, NN / 128, HH);
            mgemm<128, 128, 2, 0, false, bf16><<<gs, blk, 0, stream>>>(qk_b, cqk_b, sim,
                DHD, INNERD, INNERD, MM, DHD, DHD, NM,
                SCALE_QK, nullptr, nullptr, nullptr, nullptr, 0, 0);
        }
        // column stats from pristine sim (two-pass, 16 chunks)
        {
            dim3 g(MM / 256, HH, 16);
            colstats_part_k<<<g, blk, 0, stream>>>(sim, mcp, lcp);
        }
        colstats_comb_k<<<HH * MM / 256, blk, 0, stream>>>(mcp, lcp, mc, lc);
        // col path -> simT (transposed+mixed), then row path in place
        mixcolT_k<<<dim3(MM / 32, NN / 64), blk, 0, stream>>>(sim, simT, w_cth, mc, lc);
        rowsoftmix_k<<<NN, blk, 0, stream>>>(sim, w_th);
        // both P@V products, one launch (z=16)
        pv_k<<<dim3(1, NN / 64, 16), blk, 0, stream>>>(sim, cvT, outb_b);
    }

    // --- out-projections, one launch (z=2, ROWGAP) + bias + residual -> d_out ---
    {
        dim3 g(DIMD / 128, TOK / 128, 2);
        mgemm<128, 128, 2, 2, false, float><<<g, blk, 0, stream>>>(outb, woutT, out_x,
            INNERD, INNERD, INNERD, DIMD,
            0, (long long)DIMD * INNERD, TOK * DIMD,
            1.f, b_out, b_cout, x, context, DIMD, 0);
    }

    // --- FFN weight transposes (w4 region now free) ---
    transpose_k<float><<<dim3(FFD / 32, DIMD / 32), blk, 0, stream>>>(ffw1, ffw1T, DIMD, FFD);
    transpose_k<float><<<dim3(FFD / 32, DIMD / 32), blk, 0, stream>>>(cffw1, cffw1T, DIMD, FFD);
    transpose_k<float><<<dim3(DIMD / 32, FFD / 32), blk, 0, stream>>>(ffw2, ffw2T, FFD, DIMD);
    transpose_k<float><<<dim3(DIMD / 32, FFD / 32), blk, 0, stream>>>(cffw2, cffw2T, FFD, DIMD);

    // --- FFN per model: LN -> bias-preadd -> 256^2 8-phase GEMM1(+gelu)
    //     -> 256^2 8-phase split-K GEMM2 (atomic) ---
    const float* g_[2] = {ffg, cffg};
    const float* bterm_[2] = {ffb, cffb};
    const float* b1_[2] = {ffb1, cffb1};
    const float* b2_[2] = {ffb2, cffb2};
    const bf16* w1T_[2] = {ffw1T, cffw1T};
    const bf16* w2T_[2] = {ffw2T, cffw2T};
    float* outp_[2] = {out_x, out_c};
    bf16* lnb = xn;
    bf16* hid = sim;  // [4096][8192]
    for (int m = 0; m < 2; m++) {
        layernorm_k<<<TOK, blk, 0, stream>>>(outp_[m], lnb, g_[m], bterm_[m]);
        biasadd_k<<<TOK * DIMD / 1024, blk, 0, stream>>>(outp_[m], b2_[m]);
        {
            // GEMM1: [4096x1024] @ [1024x8192]^T -> gelu -> hid (bf16)
            dim3 g(FFD / 256, TOK / 256, 1);  // 32 x 16 = 512 wg (nwg%8==0)
            mgemm256<true, false, bf16><<<g, dim3(512), 0, stream>>>(lnb, w1T_[m], hid,
                DIMD, DIMD, DIMD, FFD, 0, 0, 0, b1_[m]);
        }
        {
            // GEMM2: split-K=4 (z offsets A,B by z*2048 in k); atomicAdd into d_out
            dim3 g(DIMD / 256, TOK / 256, 4);  // 4 x 16 x 4 = 256 wg (1/CU exactly)
            mgemm256<false, true, float><<<g, dim3(512), 0, stream>>>(hid, w2T_[m], outp_[m],
                FFD / 4, FFD, FFD, DIMD, 2048, 2048, 0, nullptr);
        }
    }
}

// Round 3
// 1182.256 us; speedup vs baseline: 1.3141x; 1.0115x over previous
//
#include <hip/hip_runtime.h>
#include <hip/hip_bf16.h>
#include <math.h>

#define BB 2
#define NN 2048
#define MM 2048
#define DIMD 1024
#define HH 8
#define DHD 64
#define INNERD 512
#define FFD 8192
#define SCALE_QK 0.125f
#define LOG2E 1.44269504088896f

typedef __hip_bfloat16 bf16;
typedef float f32x4 __attribute__((ext_vector_type(4)));
typedef short short8 __attribute__((ext_vector_type(8)));
static const long long NM = (long long)NN * MM;

__device__ __forceinline__ float cvt(float v) { return v; }
__device__ __forceinline__ float cvt(bf16 v) { return __bfloat162float(v); }
__device__ __forceinline__ void stc(float* p, float v) { *p = v; }
__device__ __forceinline__ void stc(bf16* p, float v) { *p = __float2bfloat16(v); }

__device__ __forceinline__ float bits2f(short u) {
    return __uint_as_float(((unsigned)(unsigned short)u) << 16);
}
__device__ __forceinline__ short bf16bits(float f) {
    bf16 t = __float2bfloat16(f);
    short s;
    __builtin_memcpy(&s, &t, 2);
    return s;
}

// branch-free gelu: 0.5*v*(1+erf(v/sqrt2)), erf via A&S 7.1.26 (|eps|<=1.5e-7)
__device__ __forceinline__ float gelu_f(float v) {
    float z = fabsf(v) * 0.70710678118654752440f;
    float t = __builtin_amdgcn_rcpf(__builtin_fmaf(0.3275911f, z, 1.0f));
    float inner = __builtin_fmaf(
        t, __builtin_fmaf(t, __builtin_fmaf(t, __builtin_fmaf(t, 1.061405429f, -1.453152027f),
                                            1.421413741f), -0.284496736f), 0.254829592f);
    float p = t * inner;
    float e = exp2f(-z * z * LOG2E);
    float erfz = __builtin_fmaf(-p, e, 1.0f);
    return 0.5f * v * (1.0f + copysignf(erfz, v));
}

__device__ __forceinline__ void gl_lds16(const bf16* g, bf16* l) {
    __builtin_amdgcn_global_load_lds(
        (const __attribute__((address_space(1))) void*)(g),
        (__attribute__((address_space(3))) void*)(l), 16, 0, 0);
}

// ---------------- reductions ----------------
__device__ __forceinline__ float block_reduce_sum(float v) {
    __shared__ float sh[4];
    int tid = threadIdx.x;
#pragma unroll
    for (int off = 32; off > 0; off >>= 1) v += __shfl_down(v, off, 64);
    __syncthreads();
    if ((tid & 63) == 0) sh[tid >> 6] = v;
    __syncthreads();
    return sh[0] + sh[1] + sh[2] + sh[3];
}

// ---------------- layernorm: fp32 in -> bf16 out ----------------
__global__ __launch_bounds__(256) void layernorm_k(const float* __restrict__ in,
                                                   bf16* __restrict__ out,
                                                   const float* __restrict__ g,
                                                   const float* __restrict__ b) {
    long long row = blockIdx.x;
    const float* xr = in + row * DIMD;
    bf16* yr = out + row * DIMD;
    int tid = threadIdx.x;
    float s = 0.f;
    for (int i = tid; i < DIMD; i += 256) s += xr[i];
    float mean = block_reduce_sum(s) * (1.0f / DIMD);
    float s2 = 0.f;
    for (int i = tid; i < DIMD; i += 256) { float d = xr[i] - mean; s2 += d * d; }
    float var = block_reduce_sum(s2) * (1.0f / DIMD);
    float inv = 1.0f / sqrtf(var + 1e-5f);
    for (int i = tid; i < DIMD; i += 256)
        yr[i] = __float2bfloat16((xr[i] - mean) * inv * g[i] + b[i]);
}

// ---------------- bias add (fp32, vectorized) ----------------
__global__ __launch_bounds__(256) void biasadd_k(float* __restrict__ out,
                                                 const float* __restrict__ bias) {
    long long idx = (long long)blockIdx.x * 256 + threadIdx.x;  // float4 index
    f32x4 v = ((f32x4*)out)[idx];
    const f32x4 bv = ((const f32x4*)bias)[idx & (DIMD / 4 - 1)];
    v.x += bv.x; v.y += bv.y; v.z += bv.z; v.w += bv.w;
    ((f32x4*)out)[idx] = v;
}

// ---------------- merge split-K partial: out += pp ----------------
__global__ __launch_bounds__(256) void addmerge_k(float* __restrict__ out,
                                                  const float* __restrict__ pp) {
    long long idx = (long long)blockIdx.x * 256 + threadIdx.x;  // float4 index
    f32x4 a = ((f32x4*)out)[idx];
    f32x4 b = ((const f32x4*)pp)[idx];
    a.x += b.x; a.y += b.y; a.z += b.z; a.w += b.w;
    ((f32x4*)out)[idx] = a;
}

// ---------------- transpose + convert: in [R][C] -> out bf16 [C][R] ----------------
template <typename TI>
__global__ __launch_bounds__(256) void transpose_k(const TI* __restrict__ in,
                                                   bf16* __restrict__ out,
                                                   int R, int C) {
    __shared__ bf16 t[32][33];
    int bc = blockIdx.x * 32, br = blockIdx.y * 32;
    int tid = threadIdx.x;
    int c = tid & 31, r0 = tid >> 5;
#pragma unroll
    for (int s = 0; s < 4; s++) {
        int r = r0 + s * 8;
        t[r][c] = __float2bfloat16(cvt(in[(long long)(br + r) * C + bc + c]));
    }
    __syncthreads();
#pragma unroll
    for (int s = 0; s < 4; s++) {
        int r = r0 + s * 8;
        out[(long long)(bc + r) * R + br + c] = t[c][r];
    }
}

// ---------------- col softmax stats over i: partial (two-pass) then combine ----------------
__global__ __launch_bounds__(256) void colstats_part_k(const bf16* __restrict__ sim,
                                                       float* __restrict__ mcp,
                                                       float* __restrict__ lcp) {
    int j = blockIdx.x * 256 + threadIdx.x;
    int h = blockIdx.y;
    int ic = blockIdx.z;
    const bf16* base = sim + (long long)h * NM + (long long)ic * 128 * MM + j;
    float m = -3.4e38f;
#pragma unroll 8
    for (int i = 0; i < 128; i++) m = fmaxf(m, cvt(base[(long long)i * MM]));
    float s = 0.f;
#pragma unroll 8
    for (int i = 0; i < 128; i++)
        s += exp2f((cvt(base[(long long)i * MM]) - m) * LOG2E);
    mcp[((long long)ic * HH + h) * MM + j] = m;
    lcp[((long long)ic * HH + h) * MM + j] = s;
}

__global__ __launch_bounds__(256) void colstats_comb_k(const float* __restrict__ mcp,
                                                       const float* __restrict__ lcp,
                                                       float* __restrict__ mc,
                                                       float* __restrict__ lc) {
    int idx = blockIdx.x * 256 + threadIdx.x;  // h*MM + j
    int h = idx >> 11, j = idx & (MM - 1);
    float m = -3.4e38f;
#pragma unroll
    for (int ic = 0; ic < 16; ic++) m = fmaxf(m, mcp[((long long)ic * HH + h) * MM + j]);
    float l = 0.f;
#pragma unroll
    for (int ic = 0; ic < 16; ic++)
        l += lcp[((long long)ic * HH + h) * MM + j] *
             exp2f((mcp[((long long)ic * HH + h) * MM + j] - m) * LOG2E);
    mc[idx] = m;
    lc[idx] = l;
}

// ---------------- col path: normalize + mix + transpose, sim -> simT ----------------
__global__ __launch_bounds__(256) void mixcolT_k(const bf16* __restrict__ sim,
                                                 bf16* __restrict__ simT,
                                                 const float* __restrict__ w,
                                                 const float* __restrict__ mc,
                                                 const float* __restrict__ lc) {
    __shared__ __align__(16) bf16 t[HH * 64 * 32];
    __shared__ float ws_[64];
    int j0 = blockIdx.x * 32, i0 = blockIdx.y * 64;
    int tid = threadIdx.x;
    if (tid < 64) ws_[tid] = w[tid];
#pragma unroll
    for (int q = 0; q < 8; q++) {
        int c = q * 256 + tid;  // [h(8)][r(64)][jc(4)]
        int h = c >> 8, r = (c >> 2) & 63, jc = c & 3;
        short8 x = *(const short8*)&sim[(long long)h * NM + (long long)(i0 + r) * MM + j0 + jc * 8];
        *(short8*)&t[h * 2048 + r * 32 + (jc ^ ((r >> 3) & 3)) * 8] = x;
    }
    __syncthreads();
    int jl = tid >> 3, io = tid & 7;
    int jg = j0 + jl;
    float e[HH][8];
#pragma unroll
    for (int h = 0; h < HH; h++) {
        float mcj = mc[h * MM + jg];
        float rl = 1.0f / lc[h * MM + jg];
#pragma unroll
        for (int k = 0; k < 8; k++) {
            int il = io * 8 + k;
            float v = cvt(t[h * 2048 + il * 32 + (((jl >> 3) ^ io) & 3) * 8 + (jl & 7)]);
            e[h][k] = exp2f((v - mcj) * LOG2E) * rl;
        }
    }
#pragma unroll
    for (int g = 0; g < HH; g++) {
        short8 o;
#pragma unroll
        for (int k = 0; k < 8; k++) {
            float acc = 0.f;
#pragma unroll
            for (int h = 0; h < HH; h++) acc += ws_[g * 8 + h] * e[h][k];
            o[k] = bf16bits(acc);
        }
        *(short8*)&simT[(long long)g * NM + (long long)jg * MM + i0 + io * 8] = o;
    }
}

// ---------------- row path: fused row-stats + normalize + mix, in place ----------------
__global__ __launch_bounds__(256) void rowsoftmix_k(bf16* __restrict__ sim,
                                                    const float* __restrict__ w) {
    __shared__ float ws_[64];
    __shared__ float redm[HH][4];
    __shared__ float redl[HH][4];
    long long i = blockIdx.x;
    int tid = threadIdx.x, lane = tid & 63, wv = tid >> 6;
    if (tid < 64) ws_[tid] = w[tid];
    bf16* rowbase = sim + i * MM + tid * 8;
    float v[HH][8];
#pragma unroll
    for (int h = 0; h < HH; h++) {
        short8 r = *(const short8*)(rowbase + (long long)h * NM);
#pragma unroll
        for (int c = 0; c < 8; c++) v[h][c] = bits2f(r[c]);
    }
    float mh[HH];
#pragma unroll
    for (int h = 0; h < HH; h++) {
        float m = fmaxf(fmaxf(fmaxf(v[h][0], v[h][1]), fmaxf(v[h][2], v[h][3])),
                        fmaxf(fmaxf(v[h][4], v[h][5]), fmaxf(v[h][6], v[h][7])));
#pragma unroll
        for (int off = 32; off > 0; off >>= 1) m = fmaxf(m, __shfl_xor(m, off, 64));
        if (lane == 0) redm[h][wv] = m;
    }
    __syncthreads();
#pragma unroll
    for (int h = 0; h < HH; h++)
        mh[h] = fmaxf(fmaxf(redm[h][0], redm[h][1]), fmaxf(redm[h][2], redm[h][3]));
#pragma unroll
    for (int h = 0; h < HH; h++) {
        float s = 0.f;
#pragma unroll
        for (int c = 0; c < 8; c++) {
            v[h][c] = exp2f((v[h][c] - mh[h]) * LOG2E);
            s += v[h][c];
        }
#pragma unroll
        for (int off = 32; off > 0; off >>= 1) s += __shfl_xor(s, off, 64);
        if (lane == 0) redl[h][wv] = s;
    }
    __syncthreads();
#pragma unroll
    for (int h = 0; h < HH; h++) {
        float inv = 1.0f / (redl[h][0] + redl[h][1] + redl[h][2] + redl[h][3]);
#pragma unroll
        for (int c = 0; c < 8; c++) v[h][c] *= inv;
    }
#pragma unroll
    for (int g = 0; g < HH; g++) {
        short8 o;
#pragma unroll
        for (int c = 0; c < 8; c++) {
            float acc = 0.f;
#pragma unroll
            for (int h = 0; h < HH; h++) acc += ws_[g * 8 + h] * v[h][c];
            o[c] = bf16bits(acc);
        }
        *(short8*)(rowbase + (long long)g * NM) = o;
    }
}

// ---------------- MFMA bf16 GEMM (128^2, 2-barrier; small/odd shapes) ----------------
template <int BM, int BN, int WROWS, int ZMODE, bool ATOMIC, typename CT>
__global__ __launch_bounds__(256) void mgemm(
    const bf16* __restrict__ A, const bf16* __restrict__ B, CT* __restrict__ C,
    int K, int lda, int ldb, int ldc,
    long long sA, long long sB, long long sC,
    float alpha, const float* __restrict__ bias, const float* __restrict__ bias2,
    const float* __restrict__ residual, const float* __restrict__ residual2,
    int ldr, int gelu_flag) {
    constexpr int BK = 32;
    constexpr int WCOLS = 4 / WROWS;
    constexpr int WM = BM / WROWS, WN = BN / WCOLS;
    constexpr int FM = WM / 16, FN = WN / 16;
    constexpr int ACH = BM * BK / 8;
    constexpr int BCH = BN * BK / 8;
    __shared__ bf16 As[BM * BK];
    __shared__ bf16 Bs[BN * BK];
    int z = blockIdx.z;
    int m0 = blockIdx.y * BM, n0 = blockIdx.x * BN;
    if (ZMODE == 0) A += z * sA;
    else if (ZMODE == 1) A += (long long)(z >> 1) * sA;
    else if (ZMODE == 2) A += ((long long)(((m0 >> 11) << 1) + z) * 2048 - m0) * lda;
    B += z * sB;
    C += z * sC;
    const float* bb_ = bias;
    const float* rr_ = residual;
    if (ZMODE == 2 && z) { bb_ = bias2; rr_ = residual2; }
    int tid = threadIdx.x, lane = tid & 63, w = tid >> 6;
    int wm = (w / WCOLS) * WM, wn = (w % WCOLS) * WN;
    f32x4 acc[FM][FN] = {};
    for (int k0 = 0; k0 < K; k0 += BK) {
        __syncthreads();
#pragma unroll
        for (int c = tid; c < ACH; c += 256) {
            int row = c >> 2, col = (c & 3) * 8;
            gl_lds16(A + (long long)(m0 + row) * lda + k0 + col, As + c * 8);
        }
#pragma unroll
        for (int c = tid; c < BCH; c += 256) {
            int row = c >> 2, col = (c & 3) * 8;
            gl_lds16(B + (long long)(n0 + row) * ldb + k0 + col, Bs + c * 8);
        }
        __syncthreads();
        short8 af[FM], bfr[FN];
#pragma unroll
        for (int fm = 0; fm < FM; fm++)
            af[fm] = *(const short8*)&As[(wm + fm * 16 + (lane & 15)) * BK + (lane >> 4) * 8];
#pragma unroll
        for (int fn = 0; fn < FN; fn++)
            bfr[fn] = *(const short8*)&Bs[(wn + fn * 16 + (lane & 15)) * BK + (lane >> 4) * 8];
#pragma unroll
        for (int fm = 0; fm < FM; fm++)
#pragma unroll
            for (int fn = 0; fn < FN; fn++)
                acc[fm][fn] = __builtin_amdgcn_mfma_f32_16x16x32_bf16(af[fm], bfr[fn], acc[fm][fn], 0, 0, 0);
    }
#pragma unroll
    for (int fm = 0; fm < FM; fm++) {
#pragma unroll
        for (int fn = 0; fn < FN; fn++) {
#pragma unroll
            for (int r = 0; r < 4; r++) {
                int m = m0 + wm + fm * 16 + (lane >> 4) * 4 + r;
                int n = n0 + wn + fn * 16 + (lane & 15);
                float v = acc[fm][fn][r] * alpha;
                if (bb_) v += bb_[n];
                if (rr_) v += rr_[(long long)m * ldr + n];
                if (gelu_flag) v = gelu_f(v);
                if (ATOMIC) atomicAdd((float*)&C[(long long)m * ldc + n], v);
                else stc(&C[(long long)m * ldc + n], v);
            }
        }
    }
}

// ---------------- 256x256 8-phase MFMA GEMM (T2+T3+T4+T5) ----------------
// CMODE 0: plain store to C. CMODE 1: split-2; z==0 -> C += v in place (single writer),
// z==1 -> plain store partial to C2 (merged later by addmerge_k).
template <bool GELU, int CMODE, typename CT>
__global__ __launch_bounds__(512, 2) void mgemm256(
    const bf16* __restrict__ A, const bf16* __restrict__ B, CT* __restrict__ C,
    CT* __restrict__ C2,
    int K, int lda, int ldb, int ldc,
    long long sA, long long sB, long long sC,
    const float* __restrict__ bias) {
    __shared__ bf16 sm[65536];
    const int T = K >> 6;  // K-tiles of 64
    int z = blockIdx.z;
    A += (long long)z * sA;
    B += (long long)z * sB;
    C += (long long)z * sC;
    int gx = gridDim.x;
    int nwg = gx * gridDim.y;
    int id = blockIdx.y * gx + blockIdx.x;
    id = (id & 7) * (nwg >> 3) + (id >> 3);
    int n0 = (id % gx) * 256;
    int m0 = (id / gx) * 256;

    int tid = threadIdx.x, lane = tid & 63, w = tid >> 6;
    int wrow = w >> 2, wcol = w & 3;
    int sr = tid >> 3;                       // 0..63
    int ecol = (((tid >> 3) ^ tid) & 7) * 8; // pre-swizzled global col (elements)

    auto stage = [&](const bf16* g, int ld, int row0, int k0, bf16* l) {
        const bf16* s = g + (long long)(row0 + sr) * ld + k0 + ecol;
        gl_lds16(s, l + (tid << 3));
        gl_lds16(s + (long long)(ld << 6), l + 4096 + (tid << 3));
    };

    f32x4 acc[8][4] = {};

    stage(A, lda, m0, 0, sm);
    stage(A, lda, m0 + 128, 0, sm + 8192);
    stage(B, ldb, n0, 0, sm + 32768);
    stage(B, ldb, n0 + 128, 0, sm + 32768 + 8192);
    if (T > 1) {
        stage(B, ldb, n0, 64, sm + 32768 + 16384);
        stage(B, ldb, n0 + 128, 64, sm + 32768 + 16384 + 8192);
        asm volatile("s_waitcnt vmcnt(4)" ::: "memory");
    } else {
        asm volatile("s_waitcnt vmcnt(0)" ::: "memory");
    }
    __builtin_amdgcn_s_barrier();

    for (int kt = 0; kt < T; ++kt) {
        const int cur = kt & 1, nxt = cur ^ 1;
        const bf16* Ab = sm + cur * 16384;
        const bf16* Bb = sm + 32768 + cur * 16384;
        short8 bf_[4][2];
#pragma unroll
        for (int fn = 0; fn < 4; fn++)
#pragma unroll
            for (int kk = 0; kk < 2; kk++) {
                int row = wcol * 64 + fn * 16 + (lane & 15);
                int cb = (kk * 64 + ((lane >> 4) << 4)) ^ ((row & 7) << 4);
                bf_[fn][kk] = *(const short8*)((const char*)Bb + row * 128 + cb);
            }
#pragma unroll
        for (int q = 0; q < 4; q++) {
            short8 af[2][2];
#pragma unroll
            for (int i = 0; i < 2; i++)
#pragma unroll
                for (int kk = 0; kk < 2; kk++) {
                    int row = wrow * 128 + (q * 2 + i) * 16 + (lane & 15);
                    int cb = (kk * 64 + ((lane >> 4) << 4)) ^ ((row & 7) << 4);
                    af[i][kk] = *(const short8*)((const char*)Ab + row * 128 + cb);
                }
            if (q == 0) {
                if (kt + 1 < T) stage(A, lda, m0, (kt + 1) << 6, sm + nxt * 16384);
            } else if (q == 1) {
                if (kt + 1 < T) stage(A, lda, m0 + 128, (kt + 1) << 6, sm + nxt * 16384 + 8192);
            } else if (q == 2) {
                if (kt + 2 < T) stage(B, ldb, n0, (kt + 2) << 6, sm + 32768 + cur * 16384);
            } else {
                if (kt + 2 < T) {
                    stage(B, ldb, n0 + 128, (kt + 2) << 6, sm + 32768 + cur * 16384 + 8192);
                    asm volatile("s_waitcnt vmcnt(4)" ::: "memory");
                } else {
                    asm volatile("s_waitcnt vmcnt(0)" ::: "memory");
                }
            }
            __builtin_amdgcn_s_barrier();
            __builtin_amdgcn_s_setprio(1);
#pragma unroll
            for (int i = 0; i < 2; i++)
#pragma unroll
                for (int fn = 0; fn < 4; fn++)
#pragma unroll
                    for (int kk = 0; kk < 2; kk++)
                        acc[q * 2 + i][fn] = __builtin_amdgcn_mfma_f32_16x16x32_bf16(
                            af[i][kk], bf_[fn][kk], acc[q * 2 + i][fn], 0, 0, 0);
            __builtin_amdgcn_s_setprio(0);
            __builtin_amdgcn_s_barrier();
        }
    }

    long long crow0 = m0 + wrow * 128 + ((lane >> 4) << 2);
    int ccol0 = n0 + wcol * 64 + (lane & 15);
    float bcol[4] = {0.f, 0.f, 0.f, 0.f};
    if (bias) {
#pragma unroll
        for (int fn = 0; fn < 4; fn++) bcol[fn] = bias[ccol0 + fn * 16];
    }
#pragma unroll
    for (int fm = 0; fm < 8; fm++)
#pragma unroll
        for (int fn = 0; fn < 4; fn++)
#pragma unroll
            for (int r = 0; r < 4; r++) {
                long long m = crow0 + fm * 16 + r;
                int n = ccol0 + fn * 16;
                float v = acc[fm][fn][r] + bcol[fn];
                if (GELU) v = gelu_f(v);
                if (CMODE == 1) {
                    if (z == 0) {
                        C[m * ldc + n] += v;      // single writer per element
                    } else {
                        stc(&C2[m * ldc + n], v); // partial, merged later
                    }
                } else {
                    stc(&C[m * ldc + n], v);
                }
            }
}

// ---------------- attention P@V, both paths in one launch ----------------
__global__ __launch_bounds__(256) void pv_k(const bf16* __restrict__ P,
                                            const bf16* __restrict__ Vt,
                                            bf16* __restrict__ O) {
    constexpr int BK = 32;
    __shared__ bf16 As[64 * BK];
    __shared__ bf16 Bs[64 * BK];
    int z = blockIdx.z;
    int h = z & 7, sel = z >> 3;
    const bf16* A = P + (long long)z * NM;
    const bf16* B = Vt + (long long)z * DHD * NN;
    bf16* C = O + (long long)sel * NN * INNERD + h * DHD;
    int m0 = blockIdx.y * 64;
    int tid = threadIdx.x, lane = tid & 63, w = tid >> 6;
    int wm = w * 16;
    f32x4 acc[4] = {};
    for (int k0 = 0; k0 < NN; k0 += BK) {
        __syncthreads();
        {
            int row = tid >> 2, col = (tid & 3) * 8;
            gl_lds16(A + (long long)(m0 + row) * MM + k0 + col, As + tid * 8);
            gl_lds16(B + (long long)row * NN + k0 + col, Bs + tid * 8);
        }
        __syncthreads();
        short8 af = *(const short8*)&As[(wm + (lane & 15)) * BK + (lane >> 4) * 8];
#pragma unroll
        for (int fn = 0; fn < 4; fn++) {
            short8 bfr = *(const short8*)&Bs[(fn * 16 + (lane & 15)) * BK + (lane >> 4) * 8];
            acc[fn] = __builtin_amdgcn_mfma_f32_16x16x32_bf16(af, bfr, acc[fn], 0, 0, 0);
        }
    }
#pragma unroll
    for (int fn = 0; fn < 4; fn++)
#pragma unroll
        for (int r = 0; r < 4; r++) {
            int m = m0 + wm + (lane >> 4) * 4 + r;
            int n = fn * 16 + (lane & 15);
            stc(&C[(long long)m * INNERD + n], acc[fn][r]);
        }
}

extern "C" void kernel_launch(void* const* d_in, const int* in_sizes, int n_in,
                              void* d_out, int out_size, void* d_ws, size_t ws_size,
                              hipStream_t stream) {
    const float* x = (const float*)d_in[0];
    const float* context = (const float*)d_in[1];
    const float* gx = (const float*)d_in[4];
    const float* bx = (const float*)d_in[5];
    const float* gc = (const float*)d_in[6];
    const float* bc = (const float*)d_in[7];
    const float* w_qk = (const float*)d_in[8];
    const float* w_cqk = (const float*)d_in[9];
    const float* w_v = (const float*)d_in[10];
    const float* w_cv = (const float*)d_in[11];
    const float* w_out = (const float*)d_in[12];
    const float* b_out = (const float*)d_in[13];
    const float* w_cout = (const float*)d_in[14];
    const float* b_cout = (const float*)d_in[15];
    const float* w_th = (const float*)d_in[16];
    const float* w_cth = (const float*)d_in[17];
    const float* ffg = (const float*)d_in[18];
    const float* ffb = (const float*)d_in[19];
    const float* ffw1 = (const float*)d_in[20];
    const float* ffb1 = (const float*)d_in[21];
    const float* ffw2 = (const float*)d_in[22];
    const float* ffb2 = (const float*)d_in[23];
    const float* cffg = (const float*)d_in[24];
    const float* cffb = (const float*)d_in[25];
    const float* cffw1 = (const float*)d_in[26];
    const float* cffb1 = (const float*)d_in[27];
    const float* cffw2 = (const float*)d_in[28];
    const float* cffb2 = (const float*)d_in[29];

    const long long TOK = (long long)BB * NN;   // 4096

    // ---- workspace layout ----
    bf16* xn = (bf16*)d_ws;                       // 4 M elems
    bf16* cn = xn + TOK * DIMD;                   // 4 M (right after xn: AHALF)
    bf16* qk = cn + TOK * DIMD;                   // 2 M each, order qk,vv,cqk,cv
    bf16* vv = qk + TOK * INNERD;
    bf16* cqk = vv + TOK * INNERD;
    bf16* cv = cqk + TOK * INNERD;
    bf16* outb = cv + TOK * INNERD;               // [B][2][NN][INNERD] = 4 M
    bf16* sim = outb + (long long)BB * 2 * NN * INNERD;  // 32 M (8 planes)
    bf16* w4 = sim + (long long)HH * NM;          // 32 M: simT during attention;
    bf16* ffw1T = w4;                             //   then ffw1T,cffw1T,ffw2T,cffw2T
    bf16* cffw1T = ffw1T + (long long)FFD * DIMD;
    bf16* ffw2T = cffw1T + (long long)FFD * DIMD;
    bf16* cffw2T = ffw2T + (long long)DIMD * FFD;
    bf16* simT = w4;                              // alias (attention phase only)
    bf16* wqkT = w4 + 4LL * FFD * DIMD;           // 0.5 M each, order for proj z
    bf16* wvT = wqkT + (long long)INNERD * DIMD;
    bf16* wcqkT = wvT + (long long)INNERD * DIMD;
    bf16* wcvT = wcqkT + (long long)INNERD * DIMD;
    bf16* woutT = wcvT + (long long)INNERD * DIMD;
    bf16* wcoutT = woutT + (long long)DIMD * INNERD;
    bf16* cvT = wcoutT + (long long)DIMD * INNERD;  // order cvT then vT for pv z-map
    bf16* vT = cvT + (long long)INNERD * NN;
    float* stats = (float*)(vT + (long long)INNERD * NN);
    float* mc = stats;                 // 8*2048
    float* lc = mc + HH * MM;
    float* mcp = lc + HH * MM;         // 16*8*2048
    float* lcp = mcp + 16 * HH * MM;
    // FFN-phase alias: split-K partial buffer (16 MB) over the attention proj buffers
    float* pp = (float*)qk;            // [TOK][DIMD] f32 = qk..cv region exactly

    float* out_x = (float*)d_out;
    float* out_c = out_x + TOK * DIMD;

    dim3 blk(256);

    // --- small weight transposes (proj + out-proj) ---
    transpose_k<float><<<dim3(INNERD / 32, DIMD / 32), blk, 0, stream>>>(w_qk, wqkT, DIMD, INNERD);
    transpose_k<float><<<dim3(INNERD / 32, DIMD / 32), blk, 0, stream>>>(w_v, wvT, DIMD, INNERD);
    transpose_k<float><<<dim3(INNERD / 32, DIMD / 32), blk, 0, stream>>>(w_cqk, wcqkT, DIMD, INNERD);
    transpose_k<float><<<dim3(INNERD / 32, DIMD / 32), blk, 0, stream>>>(w_cv, wcvT, DIMD, INNERD);
    transpose_k<float><<<dim3(DIMD / 32, INNERD / 32), blk, 0, stream>>>(w_out, woutT, INNERD, DIMD);
    transpose_k<float><<<dim3(DIMD / 32, INNERD / 32), blk, 0, stream>>>(w_cout, wcoutT, INNERD, DIMD);

    // --- input layernorms ---
    layernorm_k<<<TOK, blk, 0, stream>>>(x, xn, gx, bx);
    layernorm_k<<<TOK, blk, 0, stream>>>(context, cn, gc, bc);

    // --- all 4 projections in one launch (z=4, AHALF) ---
    {
        dim3 g(INNERD / 128, TOK / 128, 4);
        mgemm<128, 128, 2, 1, false, bf16><<<g, blk, 0, stream>>>(xn, wqkT, qk,
            DIMD, DIMD, DIMD, INNERD,
            TOK * DIMD, (long long)INNERD * DIMD, TOK * INNERD,
            1.f, nullptr, nullptr, nullptr, nullptr, 0, 0);
    }

    // --- attention, per batch ---
    for (int b = 0; b < BB; b++) {
        const bf16* qk_b = qk + (long long)b * NN * INNERD;
        const bf16* cqk_b = cqk + (long long)b * NN * INNERD;
        const bf16* v_b = vv + (long long)b * NN * INNERD;
        const bf16* cv_b = cv + (long long)b * NN * INNERD;
        bf16* outb_b = outb + (long long)b * 2 * NN * INNERD;

        transpose_k<bf16><<<dim3(INNERD / 32, NN / 32), blk, 0, stream>>>(cv_b, cvT, NN, INNERD);
        transpose_k<bf16><<<dim3(INNERD / 32, NN / 32), blk, 0, stream>>>(v_b, vT, NN, INNERD);

        // sim[h,i,j] = SCALE * qk_h[i,:] . cqk_h[j,:]
        {
            dim3 gs(MM / 128, NN / 128, HH);
            mgemm<128, 128, 2, 0, false, bf16><<<gs, blk, 0, stream>>>(qk_b, cqk_b, sim,
                DHD, INNERD, INNERD, MM, DHD, DHD, NM,
                SCALE_QK, nullptr, nullptr, nullptr, nullptr, 0, 0);
        }
        // column stats from pristine sim (two-pass, 16 chunks)
        {
            dim3 g(MM / 256, HH, 16);
            colstats_part_k<<<g, blk, 0, stream>>>(sim, mcp, lcp);
        }
        colstats_comb_k<<<HH * MM / 256, blk, 0, stream>>>(mcp, lcp, mc, lc);
        // col path -> simT (transposed+mixed), then row path in place
        mixcolT_k<<<dim3(MM / 32, NN / 64), blk, 0, stream>>>(sim, simT, w_cth, mc, lc);
        rowsoftmix_k<<<NN, blk, 0, stream>>>(sim, w_th);
        // both P@V products, one launch (z=16)
        pv_k<<<dim3(1, NN / 64, 16), blk, 0, stream>>>(sim, cvT, outb_b);
    }

    // --- out-projections, one launch (z=2, ROWGAP) + bias + residual -> d_out ---
    {
        dim3 g(DIMD / 128, TOK / 128, 2);
        mgemm<128, 128, 2, 2, false, float><<<g, blk, 0, stream>>>(outb, woutT, out_x,
            INNERD, INNERD, INNERD, DIMD,
            0, (long long)DIMD * INNERD, TOK * DIMD,
            1.f, b_out, b_cout, x, context, DIMD, 0);
    }

    // --- FFN weight transposes (w4 region now free) ---
    transpose_k<float><<<dim3(FFD / 32, DIMD / 32), blk, 0, stream>>>(ffw1, ffw1T, DIMD, FFD);
    transpose_k<float><<<dim3(FFD / 32, DIMD / 32), blk, 0, stream>>>(cffw1, cffw1T, DIMD, FFD);
    transpose_k<float><<<dim3(DIMD / 32, FFD / 32), blk, 0, stream>>>(ffw2, ffw2T, FFD, DIMD);
    transpose_k<float><<<dim3(DIMD / 32, FFD / 32), blk, 0, stream>>>(cffw2, cffw2T, FFD, DIMD);

    // --- FFN per model: LN -> bias-preadd -> 256^2 8-phase GEMM1(+gelu)
    //     -> 256^2 8-phase split-2 GEMM2 (no atomics) -> merge ---
    const float* g_[2] = {ffg, cffg};
    const float* bterm_[2] = {ffb, cffb};
    const float* b1_[2] = {ffb1, cffb1};
    const float* b2_[2] = {ffb2, cffb2};
    const bf16* w1T_[2] = {ffw1T, cffw1T};
    const bf16* w2T_[2] = {ffw2T, cffw2T};
    float* outp_[2] = {out_x, out_c};
    bf16* lnb = xn;
    bf16* hid = sim;  // [4096][8192]
    for (int m = 0; m < 2; m++) {
        layernorm_k<<<TOK, blk, 0, stream>>>(outp_[m], lnb, g_[m], bterm_[m]);
        biasadd_k<<<TOK * DIMD / 1024, blk, 0, stream>>>(outp_[m], b2_[m]);
        {
            // GEMM1: [4096x1024] @ [1024x8192]^T -> gelu -> hid (bf16)
            dim3 g(FFD / 256, TOK / 256, 1);  // 32 x 16 = 512 wg (nwg%8==0)
            mgemm256<true, 0, bf16><<<g, dim3(512), 0, stream>>>(lnb, w1T_[m], hid,
                (bf16*)nullptr, DIMD, DIMD, DIMD, FFD, 0, 0, 0, b1_[m]);
        }
        {
            // GEMM2: split-2 (z offsets A,B by z*4096 in k); z=0 accumulates into
            // d_out (single writer), z=1 writes partial pp; no atomics.
            dim3 g(DIMD / 256, TOK / 256, 2);  // 4 x 16 x 2 = 128 wg
            mgemm256<false, 1, float><<<g, dim3(512), 0, stream>>>(hid, w2T_[m], outp_[m],
                pp, FFD / 2, FFD, FFD, DIMD, 4096, 4096, 0, nullptr);
        }
        addmerge_k<<<TOK * DIMD / 1024, blk, 0, stream>>>(outp_[m], pp);
    }
}

// Round 4
// 1099.450 us; speedup vs baseline: 1.4131x; 1.0753x over previous
//
#include <hip/hip_runtime.h>
#include <hip/hip_bf16.h>
#include <math.h>

#define BB 2
#define NN 2048
#define MM 2048
#define DIMD 1024
#define HH 8
#define DHD 64
#define INNERD 512
#define FFD 8192
#define SCALE_QK 0.125f
#define LOG2E 1.44269504088896f

typedef __hip_bfloat16 bf16;
typedef float f32x4 __attribute__((ext_vector_type(4)));
typedef short short8 __attribute__((ext_vector_type(8)));
static const long long NM = (long long)NN * MM;

__device__ __forceinline__ float cvt(float v) { return v; }
__device__ __forceinline__ float cvt(bf16 v) { return __bfloat162float(v); }
__device__ __forceinline__ void stc(float* p, float v) { *p = v; }
__device__ __forceinline__ void stc(bf16* p, float v) { *p = __float2bfloat16(v); }

__device__ __forceinline__ float bits2f(short u) {
    return __uint_as_float(((unsigned)(unsigned short)u) << 16);
}
__device__ __forceinline__ short bf16bits(float f) {
    bf16 t = __float2bfloat16(f);
    short s;
    __builtin_memcpy(&s, &t, 2);
    return s;
}

// branch-free gelu: 0.5*v*(1+erf(v/sqrt2)), erf via A&S 7.1.26 (|eps|<=1.5e-7)
__device__ __forceinline__ float gelu_f(float v) {
    float z = fabsf(v) * 0.70710678118654752440f;
    float t = __builtin_amdgcn_rcpf(__builtin_fmaf(0.3275911f, z, 1.0f));
    float inner = __builtin_fmaf(
        t, __builtin_fmaf(t, __builtin_fmaf(t, __builtin_fmaf(t, 1.061405429f, -1.453152027f),
                                            1.421413741f), -0.284496736f), 0.254829592f);
    float p = t * inner;
    float e = exp2f(-z * z * LOG2E);
    float erfz = __builtin_fmaf(-p, e, 1.0f);
    return 0.5f * v * (1.0f + copysignf(erfz, v));
}

__device__ __forceinline__ void gl_lds16(const bf16* g, bf16* l) {
    __builtin_amdgcn_global_load_lds(
        (const __attribute__((address_space(1))) void*)(g),
        (__attribute__((address_space(3))) void*)(l), 16, 0, 0);
}

// ---------------- reductions ----------------
__device__ __forceinline__ float block_reduce_sum(float v) {
    __shared__ float sh[4];
    int tid = threadIdx.x;
#pragma unroll
    for (int off = 32; off > 0; off >>= 1) v += __shfl_down(v, off, 64);
    __syncthreads();
    if ((tid & 63) == 0) sh[tid >> 6] = v;
    __syncthreads();
    return sh[0] + sh[1] + sh[2] + sh[3];
}

// ---------------- layernorm: fp32 in -> bf16 out ----------------
__global__ __launch_bounds__(256) void layernorm_k(const float* __restrict__ in,
                                                   bf16* __restrict__ out,
                                                   const float* __restrict__ g,
                                                   const float* __restrict__ b) {
    long long row = blockIdx.x;
    const float* xr = in + row * DIMD;
    bf16* yr = out + row * DIMD;
    int tid = threadIdx.x;
    float s = 0.f;
    for (int i = tid; i < DIMD; i += 256) s += xr[i];
    float mean = block_reduce_sum(s) * (1.0f / DIMD);
    float s2 = 0.f;
    for (int i = tid; i < DIMD; i += 256) { float d = xr[i] - mean; s2 += d * d; }
    float var = block_reduce_sum(s2) * (1.0f / DIMD);
    float inv = 1.0f / sqrtf(var + 1e-5f);
    for (int i = tid; i < DIMD; i += 256)
        yr[i] = __float2bfloat16((xr[i] - mean) * inv * g[i] + b[i]);
}

// ---------------- bias add (fp32, vectorized) ----------------
__global__ __launch_bounds__(256) void biasadd_k(float* __restrict__ out,
                                                 const float* __restrict__ bias) {
    long long idx = (long long)blockIdx.x * 256 + threadIdx.x;  // float4 index
    f32x4 v = ((f32x4*)out)[idx];
    const f32x4 bv = ((const f32x4*)bias)[idx & (DIMD / 4 - 1)];
    v.x += bv.x; v.y += bv.y; v.z += bv.z; v.w += bv.w;
    ((f32x4*)out)[idx] = v;
}

// ---------------- merge 3 split-K partials: out += p1+p2+p3 ----------------
__global__ __launch_bounds__(256) void addmerge3_k(float* __restrict__ out,
                                                   const float* __restrict__ p1,
                                                   const float* __restrict__ p2,
                                                   const float* __restrict__ p3) {
    long long idx = (long long)blockIdx.x * 256 + threadIdx.x;  // float4 index
    f32x4 a = ((f32x4*)out)[idx];
    f32x4 b = ((const f32x4*)p1)[idx];
    f32x4 c = ((const f32x4*)p2)[idx];
    f32x4 d = ((const f32x4*)p3)[idx];
    a.x += b.x + c.x + d.x;
    a.y += b.y + c.y + d.y;
    a.z += b.z + c.z + d.z;
    a.w += b.w + c.w + d.w;
    ((f32x4*)out)[idx] = a;
}

// ---------------- transpose + convert: in [R][C] -> out bf16 [C][R] ----------------
template <typename TI>
__global__ __launch_bounds__(256) void transpose_k(const TI* __restrict__ in,
                                                   bf16* __restrict__ out,
                                                   int R, int C) {
    __shared__ bf16 t[32][33];
    int bc = blockIdx.x * 32, br = blockIdx.y * 32;
    int tid = threadIdx.x;
    int c = tid & 31, r0 = tid >> 5;
#pragma unroll
    for (int s = 0; s < 4; s++) {
        int r = r0 + s * 8;
        t[r][c] = __float2bfloat16(cvt(in[(long long)(br + r) * C + bc + c]));
    }
    __syncthreads();
#pragma unroll
    for (int s = 0; s < 4; s++) {
        int r = r0 + s * 8;
        out[(long long)(bc + r) * R + br + c] = t[c][r];
    }
}

// ---------------- col softmax stats over i: partial (two-pass) then combine ----------------
__global__ __launch_bounds__(256) void colstats_part_k(const bf16* __restrict__ sim,
                                                       float* __restrict__ mcp,
                                                       float* __restrict__ lcp) {
    int j = blockIdx.x * 256 + threadIdx.x;
    int h = blockIdx.y;
    int ic = blockIdx.z;
    const bf16* base = sim + (long long)h * NM + (long long)ic * 128 * MM + j;
    float m = -3.4e38f;
#pragma unroll 8
    for (int i = 0; i < 128; i++) m = fmaxf(m, cvt(base[(long long)i * MM]));
    float s = 0.f;
#pragma unroll 8
    for (int i = 0; i < 128; i++)
        s += exp2f((cvt(base[(long long)i * MM]) - m) * LOG2E);
    mcp[((long long)ic * HH + h) * MM + j] = m;
    lcp[((long long)ic * HH + h) * MM + j] = s;
}

__global__ __launch_bounds__(256) void colstats_comb_k(const float* __restrict__ mcp,
                                                       const float* __restrict__ lcp,
                                                       float* __restrict__ mc,
                                                       float* __restrict__ lc) {
    int idx = blockIdx.x * 256 + threadIdx.x;  // h*MM + j
    int h = idx >> 11, j = idx & (MM - 1);
    float m = -3.4e38f;
#pragma unroll
    for (int ic = 0; ic < 16; ic++) m = fmaxf(m, mcp[((long long)ic * HH + h) * MM + j]);
    float l = 0.f;
#pragma unroll
    for (int ic = 0; ic < 16; ic++)
        l += lcp[((long long)ic * HH + h) * MM + j] *
             exp2f((mcp[((long long)ic * HH + h) * MM + j] - m) * LOG2E);
    mc[idx] = m;
    lc[idx] = l;
}

// ---------------- col path: normalize + mix + transpose, sim -> simT ----------------
__global__ __launch_bounds__(256) void mixcolT_k(const bf16* __restrict__ sim,
                                                 bf16* __restrict__ simT,
                                                 const float* __restrict__ w,
                                                 const float* __restrict__ mc,
                                                 const float* __restrict__ lc) {
    __shared__ __align__(16) bf16 t[HH * 64 * 32];
    __shared__ float ws_[64];
    int j0 = blockIdx.x * 32, i0 = blockIdx.y * 64;
    int tid = threadIdx.x;
    if (tid < 64) ws_[tid] = w[tid];
#pragma unroll
    for (int q = 0; q < 8; q++) {
        int c = q * 256 + tid;  // [h(8)][r(64)][jc(4)]
        int h = c >> 8, r = (c >> 2) & 63, jc = c & 3;
        short8 x = *(const short8*)&sim[(long long)h * NM + (long long)(i0 + r) * MM + j0 + jc * 8];
        *(short8*)&t[h * 2048 + r * 32 + (jc ^ ((r >> 3) & 3)) * 8] = x;
    }
    __syncthreads();
    int jl = tid >> 3, io = tid & 7;
    int jg = j0 + jl;
    float e[HH][8];
#pragma unroll
    for (int h = 0; h < HH; h++) {
        float mcj = mc[h * MM + jg];
        float rl = 1.0f / lc[h * MM + jg];
#pragma unroll
        for (int k = 0; k < 8; k++) {
            int il = io * 8 + k;
            float v = cvt(t[h * 2048 + il * 32 + (((jl >> 3) ^ io) & 3) * 8 + (jl & 7)]);
            e[h][k] = exp2f((v - mcj) * LOG2E) * rl;
        }
    }
#pragma unroll
    for (int g = 0; g < HH; g++) {
        short8 o;
#pragma unroll
        for (int k = 0; k < 8; k++) {
            float acc = 0.f;
#pragma unroll
            for (int h = 0; h < HH; h++) acc += ws_[g * 8 + h] * e[h][k];
            o[k] = bf16bits(acc);
        }
        *(short8*)&simT[(long long)g * NM + (long long)jg * MM + i0 + io * 8] = o;
    }
}

// ---------------- row path: fused row-stats + normalize + mix, in place ----------------
__global__ __launch_bounds__(256) void rowsoftmix_k(bf16* __restrict__ sim,
                                                    const float* __restrict__ w) {
    __shared__ float ws_[64];
    __shared__ float redm[HH][4];
    __shared__ float redl[HH][4];
    long long i = blockIdx.x;
    int tid = threadIdx.x, lane = tid & 63, wv = tid >> 6;
    if (tid < 64) ws_[tid] = w[tid];
    bf16* rowbase = sim + i * MM + tid * 8;
    float v[HH][8];
#pragma unroll
    for (int h = 0; h < HH; h++) {
        short8 r = *(const short8*)(rowbase + (long long)h * NM);
#pragma unroll
        for (int c = 0; c < 8; c++) v[h][c] = bits2f(r[c]);
    }
    float mh[HH];
#pragma unroll
    for (int h = 0; h < HH; h++) {
        float m = fmaxf(fmaxf(fmaxf(v[h][0], v[h][1]), fmaxf(v[h][2], v[h][3])),
                        fmaxf(fmaxf(v[h][4], v[h][5]), fmaxf(v[h][6], v[h][7])));
#pragma unroll
        for (int off = 32; off > 0; off >>= 1) m = fmaxf(m, __shfl_xor(m, off, 64));
        if (lane == 0) redm[h][wv] = m;
    }
    __syncthreads();
#pragma unroll
    for (int h = 0; h < HH; h++)
        mh[h] = fmaxf(fmaxf(redm[h][0], redm[h][1]), fmaxf(redm[h][2], redm[h][3]));
#pragma unroll
    for (int h = 0; h < HH; h++) {
        float s = 0.f;
#pragma unroll
        for (int c = 0; c < 8; c++) {
            v[h][c] = exp2f((v[h][c] - mh[h]) * LOG2E);
            s += v[h][c];
        }
#pragma unroll
        for (int off = 32; off > 0; off >>= 1) s += __shfl_xor(s, off, 64);
        if (lane == 0) redl[h][wv] = s;
    }
    __syncthreads();
#pragma unroll
    for (int h = 0; h < HH; h++) {
        float inv = 1.0f / (redl[h][0] + redl[h][1] + redl[h][2] + redl[h][3]);
#pragma unroll
        for (int c = 0; c < 8; c++) v[h][c] *= inv;
    }
#pragma unroll
    for (int g = 0; g < HH; g++) {
        short8 o;
#pragma unroll
        for (int c = 0; c < 8; c++) {
            float acc = 0.f;
#pragma unroll
            for (int h = 0; h < HH; h++) acc += ws_[g * 8 + h] * v[h][c];
            o[c] = bf16bits(acc);
        }
        *(short8*)(rowbase + (long long)g * NM) = o;
    }
}

// ---------------- MFMA bf16 GEMM (128^2, 2-barrier; small/odd shapes) ----------------
template <int BM, int BN, int WROWS, int ZMODE, bool ATOMIC, typename CT>
__global__ __launch_bounds__(256) void mgemm(
    const bf16* __restrict__ A, const bf16* __restrict__ B, CT* __restrict__ C,
    int K, int lda, int ldb, int ldc,
    long long sA, long long sB, long long sC,
    float alpha, const float* __restrict__ bias, const float* __restrict__ bias2,
    const float* __restrict__ residual, const float* __restrict__ residual2,
    int ldr, int gelu_flag) {
    constexpr int BK = 32;
    constexpr int WCOLS = 4 / WROWS;
    constexpr int WM = BM / WROWS, WN = BN / WCOLS;
    constexpr int FM = WM / 16, FN = WN / 16;
    constexpr int ACH = BM * BK / 8;
    constexpr int BCH = BN * BK / 8;
    __shared__ bf16 As[BM * BK];
    __shared__ bf16 Bs[BN * BK];
    int z = blockIdx.z;
    int m0 = blockIdx.y * BM, n0 = blockIdx.x * BN;
    if (ZMODE == 0) A += z * sA;
    else if (ZMODE == 1) A += (long long)(z >> 1) * sA;
    else if (ZMODE == 2) A += ((long long)(((m0 >> 11) << 1) + z) * 2048 - m0) * lda;
    B += z * sB;
    C += z * sC;
    const float* bb_ = bias;
    const float* rr_ = residual;
    if (ZMODE == 2 && z) { bb_ = bias2; rr_ = residual2; }
    int tid = threadIdx.x, lane = tid & 63, w = tid >> 6;
    int wm = (w / WCOLS) * WM, wn = (w % WCOLS) * WN;
    f32x4 acc[FM][FN] = {};
    for (int k0 = 0; k0 < K; k0 += BK) {
        __syncthreads();
#pragma unroll
        for (int c = tid; c < ACH; c += 256) {
            int row = c >> 2, col = (c & 3) * 8;
            gl_lds16(A + (long long)(m0 + row) * lda + k0 + col, As + c * 8);
        }
#pragma unroll
        for (int c = tid; c < BCH; c += 256) {
            int row = c >> 2, col = (c & 3) * 8;
            gl_lds16(B + (long long)(n0 + row) * ldb + k0 + col, Bs + c * 8);
        }
        __syncthreads();
        short8 af[FM], bfr[FN];
#pragma unroll
        for (int fm = 0; fm < FM; fm++)
            af[fm] = *(const short8*)&As[(wm + fm * 16 + (lane & 15)) * BK + (lane >> 4) * 8];
#pragma unroll
        for (int fn = 0; fn < FN; fn++)
            bfr[fn] = *(const short8*)&Bs[(wn + fn * 16 + (lane & 15)) * BK + (lane >> 4) * 8];
#pragma unroll
        for (int fm = 0; fm < FM; fm++)
#pragma unroll
            for (int fn = 0; fn < FN; fn++)
                acc[fm][fn] = __builtin_amdgcn_mfma_f32_16x16x32_bf16(af[fm], bfr[fn], acc[fm][fn], 0, 0, 0);
    }
#pragma unroll
    for (int fm = 0; fm < FM; fm++) {
#pragma unroll
        for (int fn = 0; fn < FN; fn++) {
#pragma unroll
            for (int r = 0; r < 4; r++) {
                int m = m0 + wm + fm * 16 + (lane >> 4) * 4 + r;
                int n = n0 + wn + fn * 16 + (lane & 15);
                float v = acc[fm][fn][r] * alpha;
                if (bb_) v += bb_[n];
                if (rr_) v += rr_[(long long)m * ldr + n];
                if (gelu_flag) v = gelu_f(v);
                if (ATOMIC) atomicAdd((float*)&C[(long long)m * ldc + n], v);
                else stc(&C[(long long)m * ldc + n], v);
            }
        }
    }
}

// ---------------- 256x256 8-phase MFMA GEMM (T2+T3+T4+T5) ----------------
// CMODE 0: plain store to C. CMODE 1: split-4; z==0 -> C += v in place (single
// writer), z==1/2/3 -> plain store partial to P1/P2/P3 (merged by addmerge3_k).
template <bool GELU, int CMODE, typename CT>
__global__ __launch_bounds__(512, 2) void mgemm256(
    const bf16* __restrict__ A, const bf16* __restrict__ B, CT* __restrict__ C,
    CT* __restrict__ P1, CT* __restrict__ P2, CT* __restrict__ P3,
    int K, int lda, int ldb, int ldc,
    long long sA, long long sB, long long sC,
    const float* __restrict__ bias) {
    __shared__ bf16 sm[65536];
    const int T = K >> 6;  // K-tiles of 64
    int z = blockIdx.z;
    A += (long long)z * sA;
    B += (long long)z * sB;
    C += (long long)z * sC;
    int gx = gridDim.x;
    int nwg = gx * gridDim.y;
    int id = blockIdx.y * gx + blockIdx.x;
    id = (id & 7) * (nwg >> 3) + (id >> 3);
    int n0 = (id % gx) * 256;
    int m0 = (id / gx) * 256;

    int tid = threadIdx.x, lane = tid & 63, w = tid >> 6;
    int wrow = w >> 2, wcol = w & 3;
    int sr = tid >> 3;                       // 0..63
    int ecol = (((tid >> 3) ^ tid) & 7) * 8; // pre-swizzled global col (elements)

    auto stage = [&](const bf16* g, int ld, int row0, int k0, bf16* l) {
        const bf16* s = g + (long long)(row0 + sr) * ld + k0 + ecol;
        gl_lds16(s, l + (tid << 3));
        gl_lds16(s + (long long)(ld << 6), l + 4096 + (tid << 3));
    };

    f32x4 acc[8][4] = {};

    stage(A, lda, m0, 0, sm);
    stage(A, lda, m0 + 128, 0, sm + 8192);
    stage(B, ldb, n0, 0, sm + 32768);
    stage(B, ldb, n0 + 128, 0, sm + 32768 + 8192);
    if (T > 1) {
        stage(B, ldb, n0, 64, sm + 32768 + 16384);
        stage(B, ldb, n0 + 128, 64, sm + 32768 + 16384 + 8192);
        asm volatile("s_waitcnt vmcnt(4)" ::: "memory");
    } else {
        asm volatile("s_waitcnt vmcnt(0)" ::: "memory");
    }
    __builtin_amdgcn_s_barrier();

    for (int kt = 0; kt < T; ++kt) {
        const int cur = kt & 1, nxt = cur ^ 1;
        const bf16* Ab = sm + cur * 16384;
        const bf16* Bb = sm + 32768 + cur * 16384;
        short8 bf_[4][2];
#pragma unroll
        for (int fn = 0; fn < 4; fn++)
#pragma unroll
            for (int kk = 0; kk < 2; kk++) {
                int row = wcol * 64 + fn * 16 + (lane & 15);
                int cb = (kk * 64 + ((lane >> 4) << 4)) ^ ((row & 7) << 4);
                bf_[fn][kk] = *(const short8*)((const char*)Bb + row * 128 + cb);
            }
#pragma unroll
        for (int q = 0; q < 4; q++) {
            short8 af[2][2];
#pragma unroll
            for (int i = 0; i < 2; i++)
#pragma unroll
                for (int kk = 0; kk < 2; kk++) {
                    int row = wrow * 128 + (q * 2 + i) * 16 + (lane & 15);
                    int cb = (kk * 64 + ((lane >> 4) << 4)) ^ ((row & 7) << 4);
                    af[i][kk] = *(const short8*)((const char*)Ab + row * 128 + cb);
                }
            if (q == 0) {
                if (kt + 1 < T) stage(A, lda, m0, (kt + 1) << 6, sm + nxt * 16384);
            } else if (q == 1) {
                if (kt + 1 < T) stage(A, lda, m0 + 128, (kt + 1) << 6, sm + nxt * 16384 + 8192);
            } else if (q == 2) {
                if (kt + 2 < T) stage(B, ldb, n0, (kt + 2) << 6, sm + 32768 + cur * 16384);
            } else {
                if (kt + 2 < T) {
                    stage(B, ldb, n0 + 128, (kt + 2) << 6, sm + 32768 + cur * 16384 + 8192);
                    asm volatile("s_waitcnt vmcnt(4)" ::: "memory");
                } else {
                    asm volatile("s_waitcnt vmcnt(0)" ::: "memory");
                }
            }
            __builtin_amdgcn_s_barrier();
            __builtin_amdgcn_s_setprio(1);
#pragma unroll
            for (int i = 0; i < 2; i++)
#pragma unroll
                for (int fn = 0; fn < 4; fn++)
#pragma unroll
                    for (int kk = 0; kk < 2; kk++)
                        acc[q * 2 + i][fn] = __builtin_amdgcn_mfma_f32_16x16x32_bf16(
                            af[i][kk], bf_[fn][kk], acc[q * 2 + i][fn], 0, 0, 0);
            __builtin_amdgcn_s_setprio(0);
            __builtin_amdgcn_s_barrier();
        }
    }

    long long crow0 = m0 + wrow * 128 + ((lane >> 4) << 2);
    int ccol0 = n0 + wcol * 64 + (lane & 15);
    float bcol[4] = {0.f, 0.f, 0.f, 0.f};
    if (bias) {
#pragma unroll
        for (int fn = 0; fn < 4; fn++) bcol[fn] = bias[ccol0 + fn * 16];
    }
    CT* dst = C;
    if (CMODE == 1 && z != 0) dst = (z == 1) ? P1 : (z == 2) ? P2 : P3;
#pragma unroll
    for (int fm = 0; fm < 8; fm++)
#pragma unroll
        for (int fn = 0; fn < 4; fn++)
#pragma unroll
            for (int r = 0; r < 4; r++) {
                long long m = crow0 + fm * 16 + r;
                int n = ccol0 + fn * 16;
                float v = acc[fm][fn][r] + bcol[fn];
                if (GELU) v = gelu_f(v);
                if (CMODE == 1) {
                    if (z == 0) dst[m * ldc + n] += v;  // single writer per element
                    else stc(&dst[m * ldc + n], v);     // partial, merged later
                } else {
                    stc(&dst[m * ldc + n], v);
                }
            }
}

// ---------------- attention P@V, both paths in one launch ----------------
__global__ __launch_bounds__(256) void pv_k(const bf16* __restrict__ P,
                                            const bf16* __restrict__ Vt,
                                            bf16* __restrict__ O) {
    constexpr int BK = 32;
    __shared__ bf16 As[64 * BK];
    __shared__ bf16 Bs[64 * BK];
    int z = blockIdx.z;
    int h = z & 7, sel = z >> 3;
    const bf16* A = P + (long long)z * NM;
    const bf16* B = Vt + (long long)z * DHD * NN;
    bf16* C = O + (long long)sel * NN * INNERD + h * DHD;
    int m0 = blockIdx.y * 64;
    int tid = threadIdx.x, lane = tid & 63, w = tid >> 6;
    int wm = w * 16;
    f32x4 acc[4] = {};
    for (int k0 = 0; k0 < NN; k0 += BK) {
        __syncthreads();
        {
            int row = tid >> 2, col = (tid & 3) * 8;
            gl_lds16(A + (long long)(m0 + row) * MM + k0 + col, As + tid * 8);
            gl_lds16(B + (long long)row * NN + k0 + col, Bs + tid * 8);
        }
        __syncthreads();
        short8 af = *(const short8*)&As[(wm + (lane & 15)) * BK + (lane >> 4) * 8];
#pragma unroll
        for (int fn = 0; fn < 4; fn++) {
            short8 bfr = *(const short8*)&Bs[(fn * 16 + (lane & 15)) * BK + (lane >> 4) * 8];
            acc[fn] = __builtin_amdgcn_mfma_f32_16x16x32_bf16(af, bfr, acc[fn], 0, 0, 0);
        }
    }
#pragma unroll
    for (int fn = 0; fn < 4; fn++)
#pragma unroll
        for (int r = 0; r < 4; r++) {
            int m = m0 + wm + (lane >> 4) * 4 + r;
            int n = fn * 16 + (lane & 15);
            stc(&C[(long long)m * INNERD + n], acc[fn][r]);
        }
}

extern "C" void kernel_launch(void* const* d_in, const int* in_sizes, int n_in,
                              void* d_out, int out_size, void* d_ws, size_t ws_size,
                              hipStream_t stream) {
    const float* x = (const float*)d_in[0];
    const float* context = (const float*)d_in[1];
    const float* gx = (const float*)d_in[4];
    const float* bx = (const float*)d_in[5];
    const float* gc = (const float*)d_in[6];
    const float* bc = (const float*)d_in[7];
    const float* w_qk = (const float*)d_in[8];
    const float* w_cqk = (const float*)d_in[9];
    const float* w_v = (const float*)d_in[10];
    const float* w_cv = (const float*)d_in[11];
    const float* w_out = (const float*)d_in[12];
    const float* b_out = (const float*)d_in[13];
    const float* w_cout = (const float*)d_in[14];
    const float* b_cout = (const float*)d_in[15];
    const float* w_th = (const float*)d_in[16];
    const float* w_cth = (const float*)d_in[17];
    const float* ffg = (const float*)d_in[18];
    const float* ffb = (const float*)d_in[19];
    const float* ffw1 = (const float*)d_in[20];
    const float* ffb1 = (const float*)d_in[21];
    const float* ffw2 = (const float*)d_in[22];
    const float* ffb2 = (const float*)d_in[23];
    const float* cffg = (const float*)d_in[24];
    const float* cffb = (const float*)d_in[25];
    const float* cffw1 = (const float*)d_in[26];
    const float* cffb1 = (const float*)d_in[27];
    const float* cffw2 = (const float*)d_in[28];
    const float* cffb2 = (const float*)d_in[29];

    const long long TOK = (long long)BB * NN;   // 4096

    // ---- workspace layout ----
    bf16* xn = (bf16*)d_ws;                       // 4 M elems
    bf16* cn = xn + TOK * DIMD;                   // 4 M (right after xn: AHALF)
    bf16* qk = cn + TOK * DIMD;                   // 2 M each, order qk,vv,cqk,cv
    bf16* vv = qk + TOK * INNERD;
    bf16* cqk = vv + TOK * INNERD;
    bf16* cv = cqk + TOK * INNERD;
    bf16* outb = cv + TOK * INNERD;               // [B][2][NN][INNERD] = 4 M
    bf16* sim = outb + (long long)BB * 2 * NN * INNERD;  // 32 M (8 planes)
    bf16* w4 = sim + (long long)HH * NM;          // 32 M elems = 4 x 16 MB slots
    bf16* s0 = w4;                                // FFN phase: w1T (current model)
    bf16* s1 = w4 + 1LL * FFD * DIMD;             // FFN phase: w2T (current model)
    bf16* s2 = w4 + 2LL * FFD * DIMD;             // FFN phase: partial p1 (f32)
    bf16* s3 = w4 + 3LL * FFD * DIMD;             // FFN phase: partial p2 (f32)
    bf16* simT = w4;                              // alias (attention phase only)
    bf16* wqkT = w4 + 4LL * FFD * DIMD;           // 0.5 M each, order for proj z
    bf16* wvT = wqkT + (long long)INNERD * DIMD;
    bf16* wcqkT = wvT + (long long)INNERD * DIMD;
    bf16* wcvT = wcqkT + (long long)INNERD * DIMD;
    bf16* woutT = wcvT + (long long)INNERD * DIMD;
    bf16* wcoutT = woutT + (long long)DIMD * INNERD;
    bf16* cvT = wcoutT + (long long)DIMD * INNERD;  // order cvT then vT for pv z-map
    bf16* vT = cvT + (long long)INNERD * NN;
    float* stats = (float*)(vT + (long long)INNERD * NN);
    float* mc = stats;                 // 8*2048
    float* lc = mc + HH * MM;
    float* mcp = lc + HH * MM;         // 16*8*2048
    float* lcp = mcp + 16 * HH * MM;
    // FFN-phase aliases: three 16 MB f32 partial buffers (dead regions)
    float* p1 = (float*)s2;            // w4 slot 2
    float* p2 = (float*)s3;            // w4 slot 3
    float* p3 = (float*)qk;            // qk..cv region (16 MB exactly)

    float* out_x = (float*)d_out;
    float* out_c = out_x + TOK * DIMD;

    dim3 blk(256);

    // --- small weight transposes (proj + out-proj) ---
    transpose_k<float><<<dim3(INNERD / 32, DIMD / 32), blk, 0, stream>>>(w_qk, wqkT, DIMD, INNERD);
    transpose_k<float><<<dim3(INNERD / 32, DIMD / 32), blk, 0, stream>>>(w_v, wvT, DIMD, INNERD);
    transpose_k<float><<<dim3(INNERD / 32, DIMD / 32), blk, 0, stream>>>(w_cqk, wcqkT, DIMD, INNERD);
    transpose_k<float><<<dim3(INNERD / 32, DIMD / 32), blk, 0, stream>>>(w_cv, wcvT, DIMD, INNERD);
    transpose_k<float><<<dim3(DIMD / 32, INNERD / 32), blk, 0, stream>>>(w_out, woutT, INNERD, DIMD);
    transpose_k<float><<<dim3(DIMD / 32, INNERD / 32), blk, 0, stream>>>(w_cout, wcoutT, INNERD, DIMD);

    // --- input layernorms ---
    layernorm_k<<<TOK, blk, 0, stream>>>(x, xn, gx, bx);
    layernorm_k<<<TOK, blk, 0, stream>>>(context, cn, gc, bc);

    // --- all 4 projections in one launch (z=4, AHALF) ---
    {
        dim3 g(INNERD / 128, TOK / 128, 4);
        mgemm<128, 128, 2, 1, false, bf16><<<g, blk, 0, stream>>>(xn, wqkT, qk,
            DIMD, DIMD, DIMD, INNERD,
            TOK * DIMD, (long long)INNERD * DIMD, TOK * INNERD,
            1.f, nullptr, nullptr, nullptr, nullptr, 0, 0);
    }

    // --- attention, per batch ---
    for (int b = 0; b < BB; b++) {
        const bf16* qk_b = qk + (long long)b * NN * INNERD;
        const bf16* cqk_b = cqk + (long long)b * NN * INNERD;
        const bf16* v_b = vv + (long long)b * NN * INNERD;
        const bf16* cv_b = cv + (long long)b * NN * INNERD;
        bf16* outb_b = outb + (long long)b * 2 * NN * INNERD;

        transpose_k<bf16><<<dim3(INNERD / 32, NN / 32), blk, 0, stream>>>(cv_b, cvT, NN, INNERD);
        transpose_k<bf16><<<dim3(INNERD / 32, NN / 32), blk, 0, stream>>>(v_b, vT, NN, INNERD);

        // sim[h,i,j] = SCALE * qk_h[i,:] . cqk_h[j,:]
        {
            dim3 gs(MM / 128, NN / 128, HH);
            mgemm<128, 128, 2, 0, false, bf16><<<gs, blk, 0, stream>>>(qk_b, cqk_b, sim,
                DHD, INNERD, INNERD, MM, DHD, DHD, NM,
                SCALE_QK, nullptr, nullptr, nullptr, nullptr, 0, 0);
        }
        // column stats from pristine sim (two-pass, 16 chunks)
        {
            dim3 g(MM / 256, HH, 16);
            colstats_part_k<<<g, blk, 0, stream>>>(sim, mcp, lcp);
        }
        colstats_comb_k<<<HH * MM / 256, blk, 0, stream>>>(mcp, lcp, mc, lc);
        // col path -> simT (transposed+mixed), then row path in place
        mixcolT_k<<<dim3(MM / 32, NN / 64), blk, 0, stream>>>(sim, simT, w_cth, mc, lc);
        rowsoftmix_k<<<NN, blk, 0, stream>>>(sim, w_th);
        // both P@V products, one launch (z=16)
        pv_k<<<dim3(1, NN / 64, 16), blk, 0, stream>>>(sim, cvT, outb_b);
    }

    // --- out-projections, one launch (z=2, ROWGAP) + bias + residual -> d_out ---
    {
        dim3 g(DIMD / 128, TOK / 128, 2);
        mgemm<128, 128, 2, 2, false, float><<<g, blk, 0, stream>>>(outb, woutT, out_x,
            INNERD, INNERD, INNERD, DIMD,
            0, (long long)DIMD * INNERD, TOK * DIMD,
            1.f, b_out, b_cout, x, context, DIMD, 0);
    }

    // --- FFN per model: transposes (into free w4 slots) -> LN -> bias-preadd ->
    //     256^2 8-phase GEMM1(+gelu) -> 256^2 8-phase split-4 GEMM2 (no atomics)
    //     -> merge 3 partials ---
    const float* g_[2] = {ffg, cffg};
    const float* bterm_[2] = {ffb, cffb};
    const float* b1_[2] = {ffb1, cffb1};
    const float* b2_[2] = {ffb2, cffb2};
    const float* w1_[2] = {ffw1, cffw1};
    const float* w2_[2] = {ffw2, cffw2};
    float* outp_[2] = {out_x, out_c};
    bf16* lnb = xn;
    bf16* hid = sim;  // [4096][8192]
    for (int m = 0; m < 2; m++) {
        transpose_k<float><<<dim3(FFD / 32, DIMD / 32), blk, 0, stream>>>(w1_[m], s0, DIMD, FFD);
        transpose_k<float><<<dim3(DIMD / 32, FFD / 32), blk, 0, stream>>>(w2_[m], s1, FFD, DIMD);
        layernorm_k<<<TOK, blk, 0, stream>>>(outp_[m], lnb, g_[m], bterm_[m]);
        biasadd_k<<<TOK * DIMD / 1024, blk, 0, stream>>>(outp_[m], b2_[m]);
        {
            // GEMM1: [4096x1024] @ [1024x8192]^T -> gelu -> hid (bf16)
            dim3 g(FFD / 256, TOK / 256, 1);  // 32 x 16 = 512 wg (nwg%8==0)
            mgemm256<true, 0, bf16><<<g, dim3(512), 0, stream>>>(lnb, s0, hid,
                (bf16*)nullptr, (bf16*)nullptr, (bf16*)nullptr,
                DIMD, DIMD, DIMD, FFD, 0, 0, 0, b1_[m]);
        }
        {
            // GEMM2: split-4 (z offsets A,B by z*2048 in k); z=0 accumulates into
            // d_out (single writer), z=1..3 write partials p1..p3; 256 wg = 1/CU.
            dim3 g(DIMD / 256, TOK / 256, 4);
            mgemm256<false, 1, float><<<g, dim3(512), 0, stream>>>(hid, s1, outp_[m],
                p1, p2, p3, FFD / 4, FFD, FFD, DIMD, 2048, 2048, 0, nullptr);
        }
        addmerge3_k<<<TOK * DIMD / 1024, blk, 0, stream>>>(outp_[m], p1, p2, p3);
    }
}